// Round 8
// baseline (465.537 us; speedup 1.0000x reference)
//
#include <hip/hip_runtime.h>

// MHA forward: B=2 T=2048 C=1024 H=16 D=64, causal, scale 1/sqrt(C)=1/32
// cast -> QKV gemm (2-phase dbuf) -> split-KV flash attn (8 waves/SIMD,
// swapped QK^T, native exp2, defer-max, f16 partials) -> combine -> out gemm

#define Bsz 2
#define Tsz 2048
#define Cdim 1024
#define Hn 16
#define Dh 64

typedef short bf16x8 __attribute__((ext_vector_type(8)));
typedef float f32x4 __attribute__((ext_vector_type(4)));
typedef unsigned short u16;
typedef _Float16 f16;
typedef _Float16 f16x8v __attribute__((ext_vector_type(8)));

#define MFMA(a, b, c) __builtin_amdgcn_mfma_f32_16x16x32_bf16(a, b, c, 0, 0, 0)
#define NEGINF (-__builtin_inff())
#define EXP2(x) __builtin_amdgcn_exp2f(x)

#define GLD16(g, l)                                                            \
  __builtin_amdgcn_global_load_lds((const __attribute__((address_space(1))) void*)(g), \
                                   (__attribute__((address_space(3))) void*)(l), 16, 0, 0)

__device__ __forceinline__ u16 f2bf(float f) {
  unsigned u = __builtin_bit_cast(unsigned, f);
  unsigned r = 0x7fffu + ((u >> 16) & 1u);
  return (u16)((u + r) >> 16);
}

__device__ __forceinline__ unsigned cvtpk(float lo, float hi) {
  unsigned r;
  asm("v_cvt_pk_bf16_f32 %0, %1, %2" : "=v"(r) : "v"(lo), "v"(hi));
  return r;
}

// flat f32 -> bf16 cast, 4 elems/thread
__global__ __launch_bounds__(256) void k_cast_x(const float* __restrict__ x,
                                                u16* __restrict__ xb, int n4) {
  int i = blockIdx.x * 256 + threadIdx.x;
  if (i >= n4) return;
  float4 v = reinterpret_cast<const float4*>(x)[i];
  ushort4 o;
  o.x = f2bf(v.x); o.y = f2bf(v.y); o.z = f2bf(v.z); o.w = f2bf(v.w);
  reinterpret_cast<ushort4*>(xb)[i] = o;
}

// Wq/Wk/Wv [H][C][D] f32 -> wt [(m*H+h)*D+d][C] bf16 via LDS tile transpose.
__global__ __launch_bounds__(256) void k_cast_w(const float* __restrict__ Wq,
                                                const float* __restrict__ Wk,
                                                const float* __restrict__ Wv,
                                                u16* __restrict__ wt) {
  __shared__ u16 tile[64][68];
  const int mh = blockIdx.y;
  const int m = mh >> 4, h = mh & 15;
  const float* src = (m == 0 ? Wq : m == 1 ? Wk : Wv) + (size_t)h * Cdim * Dh;
  const int c0 = blockIdx.x * 64;
  const int tid = threadIdx.x;
  const int cc = tid >> 4, d4 = (tid & 15) * 4;
#pragma unroll
  for (int i = 0; i < 4; ++i) {
    int c = i * 16 + cc;
    float4 v = *(const float4*)(src + (size_t)(c0 + c) * Dh + d4);
    tile[d4 + 0][c] = f2bf(v.x);
    tile[d4 + 1][c] = f2bf(v.y);
    tile[d4 + 2][c] = f2bf(v.z);
    tile[d4 + 3][c] = f2bf(v.w);
  }
  __syncthreads();
  const int c4 = (tid & 15) * 4, dd = tid >> 4;
#pragma unroll
  for (int i = 0; i < 4; ++i) {
    int d = i * 16 + dd;
    ushort4 o;
    o.x = tile[d][c4]; o.y = tile[d][c4 + 1];
    o.z = tile[d][c4 + 2]; o.w = tile[d][c4 + 3];
    *(ushort4*)(wt + (size_t)(mh * 64 + d) * Cdim + c0 + c4) = o;
  }
}

// QKV GEMM, 2-phase dbuf: 128x128, BK=32. Q pre-scaled by 1/32*log2e.
__global__ __launch_bounds__(256) void k_gemm_qkv(const u16* __restrict__ xb,
                                                  const u16* __restrict__ wt,
                                                  u16* __restrict__ qb,
                                                  u16* __restrict__ kb,
                                                  u16* __restrict__ vtb) {
  __shared__ __align__(16) u16 As[2][4096], Bs[2][4096];
  const int tid = threadIdx.x, lane = tid & 63, wid = tid >> 6;
  const int cl = lane & 15, kg = lane >> 4;
  const int row0 = blockIdx.y * 128, col0 = blockIdx.x * 128;
  const int wrow = (wid >> 1) * 64, wcol = (wid & 1) * 64;
  f32x4 acc[4][4] = {};
  const u16* a_src = xb + (size_t)(row0 + 32 * wid + (lane >> 2)) * Cdim + (lane & 3) * 8;
  const u16* b_src = wt + (size_t)(col0 + 32 * wid + (lane >> 2)) * Cdim + (lane & 3) * 8;

  auto stage = [&](int buf, int ke) {
    u16* Ad = &As[buf][1024 * wid];
    u16* Bd = &Bs[buf][1024 * wid];
    GLD16(a_src + ke, Ad);
    GLD16(a_src + 16 * Cdim + ke, Ad + 512);
    GLD16(b_src + ke, Bd);
    GLD16(b_src + 16 * Cdim + ke, Bd + 512);
  };

  stage(0, 0);
  __syncthreads();
  int cur = 0;
  for (int kk = 0; kk < 32; ++kk) {
    if (kk < 31) stage(cur ^ 1, (kk + 1) * 32);
    const u16* ar = &As[cur][(wrow + cl) * 32 + kg * 8];
    const u16* br = &Bs[cur][(wcol + cl) * 32 + kg * 8];
    bf16x8 af[4], bfr[4];
#pragma unroll
    for (int mi = 0; mi < 4; ++mi) af[mi] = *(const bf16x8*)(ar + mi * 512);
#pragma unroll
    for (int ni = 0; ni < 4; ++ni) bfr[ni] = *(const bf16x8*)(br + ni * 512);
#pragma unroll
    for (int mi = 0; mi < 4; ++mi)
#pragma unroll
      for (int ni = 0; ni < 4; ++ni)
        acc[mi][ni] = MFMA(af[mi], bfr[ni], acc[mi][ni]);
    __syncthreads();
    cur ^= 1;
  }
#pragma unroll
  for (int mi = 0; mi < 4; ++mi) {
#pragma unroll
    for (int ni = 0; ni < 4; ++ni) {
      int n = col0 + wcol + ni * 16 + cl;
      int m = n >> 10, h = (n >> 6) & 15, d = n & 63;
#pragma unroll
      for (int j = 0; j < 4; ++j) {
        int r = row0 + wrow + mi * 16 + kg * 4 + j;
        int b = r >> 11, t = r & 2047;
        float av = acc[mi][ni][j];
        if (m == 0) av *= 0.04508422f;  // 1/sqrt(C) * log2(e)
        u16 v = f2bf(av);
        size_t bh = (size_t)(b * Hn + h);
        if (m == 0)
          qb[(bh * Tsz + t) * Dh + d] = v;
        else if (m == 1)
          kb[(bh * Tsz + t) * Dh + d] = v;
        else
          vtb[(bh * Dh + d) * Tsz + t] = v;
      }
    }
  }
}

// ---- split-KV flash attention ----
// Grid 2048 flat: xcd=bid&7, idx=bid>>3; p=xcd+8*(idx>>6); rem=idx&63;
// t=31-(rem>>1) (longest first), half=rem&1. Block = 4 waves, wave owns 16
// q-rows of tile t, processes kv tiles [kt0,kt1). Writes unnormalized f16
// partial O (scaled 2^-8) + per-row (m+8, l*2^-8) f32.
__global__ __launch_bounds__(256, 8) void k_attn(const u16* __restrict__ qb,
                                                 const u16* __restrict__ kb,
                                                 const u16* __restrict__ vtb,
                                                 f16* __restrict__ pO0,
                                                 f16* pO1,
                                                 float2* __restrict__ ml0,
                                                 float2* __restrict__ ml1) {
  __shared__ __align__(16) u16 Plds[4][1024];
  const int lane = threadIdx.x & 63, wid = threadIdx.x >> 6;
  const int cl = lane & 15, kg = lane >> 4;
  const int xcd = blockIdx.x & 7, idx = blockIdx.x >> 3;
  const int p = xcd + 8 * (idx >> 6);
  const int rem = idx & 63;
  const int t = 31 - (rem >> 1);
  const int half = rem & 1;
  const int h = p & 15, b = p >> 4;
  const int n = t + 1, h0n = (n + 1) >> 1;
  const int kt0 = half ? h0n : 0;
  const int kt1 = half ? n : h0n;
  const int qr = t * 64 + wid * 16;
  const size_t bh = (size_t)(b * Hn + h);
  const u16* Qp = qb + bh * Tsz * Dh;
  const u16* Kp = kb + bh * Tsz * Dh;
  const u16* Vp = vtb + bh * Dh * Tsz;

  bf16x8 qa0 = *(const bf16x8*)(Qp + (size_t)(qr + cl) * Dh + kg * 8);
  bf16x8 qa1 = *(const bf16x8*)(Qp + (size_t)(qr + cl) * Dh + 32 + kg * 8);

  f32x4 o[4] = {};
  float m = NEGINF, l = 0.f;

  char* pb = (char*)&Plds[wid][0];
  const int rdoff0 = ((cl << 7) + (kg << 4)) ^ ((cl & 7) << 4);
  const int rdoff1 = ((cl << 7) + 64 + (kg << 4)) ^ ((cl & 7) << 4);
  const int rowoff = wid * 16;

  for (int kt = kt0; kt < kt1; ++kt) {
    const int k0 = kt * 64;
    bf16x8 kf[8];
#pragma unroll
    for (int nt = 0; nt < 4; ++nt) {
      const u16* kp = Kp + (size_t)(k0 + nt * 16 + cl) * Dh + kg * 8;
      kf[nt * 2] = *(const bf16x8*)kp;
      kf[nt * 2 + 1] = *(const bf16x8*)(kp + 32);
    }
    f32x4 sv[4];
    __builtin_amdgcn_s_setprio(1);
#pragma unroll
    for (int nt = 0; nt < 4; ++nt) {
      f32x4 z = {};
      z = MFMA(kf[nt * 2], qa0, z);
      z = MFMA(kf[nt * 2 + 1], qa1, z);
      sv[nt] = z;
    }
    __builtin_amdgcn_s_setprio(0);
    // V load after QK: kf dead -> register reuse; latency hidden by softmax
    bf16x8 vf[8];
#pragma unroll
    for (int dt = 0; dt < 4; ++dt) {
      const u16* vp = Vp + (size_t)(dt * 16 + cl) * Tsz + k0 + kg * 8;
      vf[dt * 2] = *(const bf16x8*)vp;
      vf[dt * 2 + 1] = *(const bf16x8*)(vp + 32);
    }
    if (kt == t) {  // diag tile mask
#pragma unroll
      for (int nt = 0; nt < 4; ++nt)
#pragma unroll
        for (int j = 0; j < 4; ++j)
          if (nt * 16 + kg * 4 + j > rowoff + cl) sv[nt][j] = NEGINF;
    }
    float tm = fmaxf(fmaxf(fmaxf(sv[0][0], sv[0][1]), fmaxf(sv[0][2], sv[0][3])),
                     fmaxf(fmaxf(sv[1][0], sv[1][1]), fmaxf(sv[1][2], sv[1][3])));
    tm = fmaxf(tm, fmaxf(fmaxf(fmaxf(sv[2][0], sv[2][1]), fmaxf(sv[2][2], sv[2][3])),
                         fmaxf(fmaxf(sv[3][0], sv[3][1]), fmaxf(sv[3][2], sv[3][3]))));
    if (!__all(tm <= m + 8.0f)) {
      tm = fmaxf(tm, __shfl_xor(tm, 16));
      tm = fmaxf(tm, __shfl_xor(tm, 32));
      float mnew = fmaxf(m, tm);
      float corr = EXP2(m - mnew);
      m = mnew;
      l *= corr;
      float c0 = __shfl(corr, kg * 4 + 0);
      float c1 = __shfl(corr, kg * 4 + 1);
      float c2 = __shfl(corr, kg * 4 + 2);
      float c3 = __shfl(corr, kg * 4 + 3);
#pragma unroll
      for (int dt = 0; dt < 4; ++dt) {
        o[dt][0] *= c0; o[dt][1] *= c1; o[dt][2] *= c2; o[dt][3] *= c3;
      }
    }
    float rs = 0.f;
#pragma unroll
    for (int nt = 0; nt < 4; ++nt)
#pragma unroll
      for (int j = 0; j < 4; ++j) {
        float pv = EXP2(sv[nt][j] - m);
        sv[nt][j] = pv;
        rs += pv;
      }
    l += rs;
#pragma unroll
    for (int nt = 0; nt < 4; ++nt) {
      uint2 pk;
      pk.x = cvtpk(sv[nt][0], sv[nt][1]);
      pk.y = cvtpk(sv[nt][2], sv[nt][3]);
      int waddr = ((cl << 7) + (nt << 5) + (kg << 3)) ^ ((cl & 7) << 4);
      *(uint2*)(pb + waddr) = pk;
    }
    bf16x8 pa0 = *(const bf16x8*)(pb + rdoff0);
    bf16x8 pa1 = *(const bf16x8*)(pb + rdoff1);
    __builtin_amdgcn_s_setprio(1);
#pragma unroll
    for (int dt = 0; dt < 4; ++dt) {
      o[dt] = MFMA(pa0, vf[dt * 2], o[dt]);
      o[dt] = MFMA(pa1, vf[dt * 2 + 1], o[dt]);
    }
    __builtin_amdgcn_s_setprio(0);
  }

  // finish lazy l reduction (sum over kg duplicates)
  l += __shfl_xor(l, 16);
  l += __shfl_xor(l, 32);
  // write partials: O*2^-8 as f16, (m+8, l*2^-8) as f32 (defer-safe range)
  f16* po = half ? pO1 : pO0;
#pragma unroll
  for (int dt = 0; dt < 4; ++dt)
#pragma unroll
    for (int j = 0; j < 4; ++j) {
      int tr = qr + kg * 4 + j;
      po[(size_t)(b * Tsz + tr) * Cdim + h * Dh + dt * 16 + cl] =
          (f16)(o[dt][j] * 0.00390625f);
    }
  if (lane < 16) {
    float2* ml = half ? ml1 : ml0;
    ml[(size_t)(b * Hn + h) * Tsz + qr + lane] = make_float2(m + 8.0f, l * 0.00390625f);
  }
}

// Combine: per q-row merge the two halves, normalize, write bf16 ob (in-place
// over pO1). 262144 threads, 16 elems each.
__global__ __launch_bounds__(256) void k_combine(const f16* __restrict__ pO0,
                                                 const f16* pO1,
                                                 const float2* __restrict__ ml0,
                                                 const float2* __restrict__ ml1,
                                                 u16* ob) {
  int g = blockIdx.x * 256 + threadIdx.x;  // 0..262143
  int q = g & 3, h = (g >> 2) & 15;
  int row = g >> 6;                        // b*2048 + trow
  int b = row >> 11, trow = row & 2047;
  size_t mli = (size_t)(b * Hn + h) * Tsz + trow;
  float2 v0 = ml0[mli], v1 = ml1[mli];
  float M = fmaxf(v0.x, v1.x);
  float w0 = exp2f(v0.x - M), w1 = exp2f(v1.x - M);
  float inv = 1.0f / (v0.y * w0 + v1.y * w1);
  w0 *= inv; w1 *= inv;
  size_t off = (size_t)row * Cdim + h * 64 + q * 16;
  f16x8v a0 = *(const f16x8v*)(pO0 + off);
  f16x8v a1 = *(const f16x8v*)(pO0 + off + 8);
  f16x8v b0 = *(const f16x8v*)(pO1 + off);
  f16x8v b1 = *(const f16x8v*)(pO1 + off + 8);
  ushort4 r0, r1, r2, r3;
  r0.x = f2bf((float)a0[0] * w0 + (float)b0[0] * w1);
  r0.y = f2bf((float)a0[1] * w0 + (float)b0[1] * w1);
  r0.z = f2bf((float)a0[2] * w0 + (float)b0[2] * w1);
  r0.w = f2bf((float)a0[3] * w0 + (float)b0[3] * w1);
  r1.x = f2bf((float)a0[4] * w0 + (float)b0[4] * w1);
  r1.y = f2bf((float)a0[5] * w0 + (float)b0[5] * w1);
  r1.z = f2bf((float)a0[6] * w0 + (float)b0[6] * w1);
  r1.w = f2bf((float)a0[7] * w0 + (float)b0[7] * w1);
  r2.x = f2bf((float)a1[0] * w0 + (float)b1[0] * w1);
  r2.y = f2bf((float)a1[1] * w0 + (float)b1[1] * w1);
  r2.z = f2bf((float)a1[2] * w0 + (float)b1[2] * w1);
  r2.w = f2bf((float)a1[3] * w0 + (float)b1[3] * w1);
  r3.x = f2bf((float)a1[4] * w0 + (float)b1[4] * w1);
  r3.y = f2bf((float)a1[5] * w0 + (float)b1[5] * w1);
  r3.z = f2bf((float)a1[6] * w0 + (float)b1[6] * w1);
  r3.w = f2bf((float)a1[7] * w0 + (float)b1[7] * w1);
  *(ushort4*)(ob + off) = r0;
  *(ushort4*)(ob + off + 4) = r1;
  *(ushort4*)(ob + off + 8) = r2;
  *(ushort4*)(ob + off + 12) = r3;
}

// Out GEMM, 2-phase dbuf: 128x64 tile, BK=32.
__global__ __launch_bounds__(256) void k_gemm_out(const u16* __restrict__ ob,
                                                  const u16* __restrict__ wob,
                                                  const float* __restrict__ bo,
                                                  float* __restrict__ out) {
  __shared__ __align__(16) u16 As[2][4096], Bs[2][2048];
  const int tid = threadIdx.x, lane = tid & 63, wid = tid >> 6;
  const int cl = lane & 15, kg = lane >> 4;
  const int row0 = blockIdx.y * 128, col0 = blockIdx.x * 64;
  const int wrow = (wid >> 1) * 64, wcol = (wid & 1) * 32;
  f32x4 acc[4][2] = {};
  const u16* a_src = ob + (size_t)(row0 + 32 * wid + (lane >> 2)) * Cdim + (lane & 3) * 8;
  const u16* b_src = wob + (size_t)(col0 + 16 * wid + (lane >> 2)) * Cdim + (lane & 3) * 8;

  auto stage = [&](int buf, int ke) {
    u16* Ad = &As[buf][1024 * wid];
    u16* Bd = &Bs[buf][512 * wid];
    GLD16(a_src + ke, Ad);
    GLD16(a_src + 16 * Cdim + ke, Ad + 512);
    GLD16(b_src + ke, Bd);
  };

  stage(0, 0);
  __syncthreads();
  int cur = 0;
  for (int kk = 0; kk < 32; ++kk) {
    if (kk < 31) stage(cur ^ 1, (kk + 1) * 32);
    const u16* ar = &As[cur][(wrow + cl) * 32 + kg * 8];
    const u16* br = &Bs[cur][(wcol + cl) * 32 + kg * 8];
    bf16x8 af[4], bfr[2];
#pragma unroll
    for (int mi = 0; mi < 4; ++mi) af[mi] = *(const bf16x8*)(ar + mi * 512);
#pragma unroll
    for (int ni = 0; ni < 2; ++ni) bfr[ni] = *(const bf16x8*)(br + ni * 512);
#pragma unroll
    for (int mi = 0; mi < 4; ++mi)
#pragma unroll
      for (int ni = 0; ni < 2; ++ni)
        acc[mi][ni] = MFMA(af[mi], bfr[ni], acc[mi][ni]);
    __syncthreads();
    cur ^= 1;
  }
#pragma unroll
  for (int mi = 0; mi < 4; ++mi) {
#pragma unroll
    for (int ni = 0; ni < 2; ++ni) {
      int n = col0 + wcol + ni * 16 + cl;
      float bias = bo[n];
#pragma unroll
      for (int j = 0; j < 4; ++j) {
        int r = row0 + wrow + mi * 16 + kg * 4 + j;
        out[(size_t)r * Cdim + n] = acc[mi][ni][j] + bias;
      }
    }
  }
}

extern "C" void kernel_launch(void* const* d_in, const int* in_sizes, int n_in,
                              void* d_out, int out_size, void* d_ws, size_t ws_size,
                              hipStream_t stream) {
  (void)in_sizes; (void)n_in; (void)out_size; (void)ws_size;
  const float* x = (const float*)d_in[0];
  const float* Wq = (const float*)d_in[1];
  const float* Wk = (const float*)d_in[2];
  const float* Wv = (const float*)d_in[3];
  const float* Wo = (const float*)d_in[4];
  const float* bo = (const float*)d_in[5];
  float* out = (float*)d_out;
  char* ws = (char*)d_ws;
  u16* xb = (u16*)(ws);                  // 8 MiB  x bf16 (dead after qkv gemm)
  u16* wt = (u16*)(ws + (8u << 20));     // 6 MiB  Wqkv^T (dead after qkv gemm)
  u16* wob = (u16*)(ws + (14u << 20));   // 2 MiB  Wo bf16
  u16* qb = (u16*)(ws + (16u << 20));    // 8 MiB  Q (pre-scaled)
  u16* kb = (u16*)(ws + (24u << 20));    // 8 MiB  K
  u16* vtb = (u16*)(ws + (32u << 20));   // 8 MiB  V^T
  u16* ob = (u16*)(ws + (40u << 20));    // 8 MiB  attn out bf16 (also pO1)
  // attn partials reuse dead xb/wt region:
  f16* pO0 = (f16*)(ws);                       // 8 MiB  [0, 8.39MB)
  float2* ml0 = (float2*)(ws + (17u << 19));   // 0.5 MiB @ 8.5 MiB
  float2* ml1 = (float2*)(ws + (19u << 19));   // 0.5 MiB @ 9.5 MiB
  f16* pO1 = (f16*)(ws + (40u << 20));         // in-place over ob

  k_cast_x<<<4096, 256, 0, stream>>>(x, xb, Bsz * Tsz * Cdim / 4);
  k_cast_x<<<1024, 256, 0, stream>>>(Wo, wob, Cdim * Cdim / 4);
  k_cast_w<<<dim3(16, 48), 256, 0, stream>>>(Wq, Wk, Wv, wt);
  k_gemm_qkv<<<dim3(24, 32), 256, 0, stream>>>(xb, wt, qb, kb, vtb);
  k_attn<<<2048, 256, 0, stream>>>(qb, kb, vtb, pO0, pO1, ml0, ml1);
  k_combine<<<1024, 256, 0, stream>>>(pO0, pO1, ml0, ml1, ob);
  k_gemm_out<<<dim3(16, 32), 256, 0, stream>>>(ob, wob, bo, out);
}

// Round 9
// 235.306 us; speedup vs baseline: 1.9784x; 1.9784x over previous
//
#include <hip/hip_runtime.h>

// MHA forward: B=2 T=2048 C=1024 H=16 D=64, causal, scale 1/sqrt(C)=1/32
// cast -> QKV gemm (2-phase dbuf) -> split-KV flash attn (4 waves/SIMD cap,
// swapped QK^T, native exp2, defer-max, f16 partials) -> combine -> out gemm

#define Bsz 2
#define Tsz 2048
#define Cdim 1024
#define Hn 16
#define Dh 64

typedef short bf16x8 __attribute__((ext_vector_type(8)));
typedef float f32x4 __attribute__((ext_vector_type(4)));
typedef unsigned short u16;
typedef _Float16 f16;
typedef _Float16 f16x8v __attribute__((ext_vector_type(8)));

#define MFMA(a, b, c) __builtin_amdgcn_mfma_f32_16x16x32_bf16(a, b, c, 0, 0, 0)
#define NEGINF (-__builtin_inff())
#define EXP2(x) __builtin_amdgcn_exp2f(x)

#define GLD16(g, l)                                                            \
  __builtin_amdgcn_global_load_lds((const __attribute__((address_space(1))) void*)(g), \
                                   (__attribute__((address_space(3))) void*)(l), 16, 0, 0)

__device__ __forceinline__ u16 f2bf(float f) {
  unsigned u = __builtin_bit_cast(unsigned, f);
  unsigned r = 0x7fffu + ((u >> 16) & 1u);
  return (u16)((u + r) >> 16);
}

__device__ __forceinline__ unsigned cvtpk(float lo, float hi) {
  unsigned r;
  asm("v_cvt_pk_bf16_f32 %0, %1, %2" : "=v"(r) : "v"(lo), "v"(hi));
  return r;
}

// flat f32 -> bf16 cast, 4 elems/thread
__global__ __launch_bounds__(256) void k_cast_x(const float* __restrict__ x,
                                                u16* __restrict__ xb, int n4) {
  int i = blockIdx.x * 256 + threadIdx.x;
  if (i >= n4) return;
  float4 v = reinterpret_cast<const float4*>(x)[i];
  ushort4 o;
  o.x = f2bf(v.x); o.y = f2bf(v.y); o.z = f2bf(v.z); o.w = f2bf(v.w);
  reinterpret_cast<ushort4*>(xb)[i] = o;
}

// Wq/Wk/Wv [H][C][D] f32 -> wt [(m*H+h)*D+d][C] bf16 via LDS tile transpose.
__global__ __launch_bounds__(256) void k_cast_w(const float* __restrict__ Wq,
                                                const float* __restrict__ Wk,
                                                const float* __restrict__ Wv,
                                                u16* __restrict__ wt) {
  __shared__ u16 tile[64][68];
  const int mh = blockIdx.y;
  const int m = mh >> 4, h = mh & 15;
  const float* src = (m == 0 ? Wq : m == 1 ? Wk : Wv) + (size_t)h * Cdim * Dh;
  const int c0 = blockIdx.x * 64;
  const int tid = threadIdx.x;
  const int cc = tid >> 4, d4 = (tid & 15) * 4;
#pragma unroll
  for (int i = 0; i < 4; ++i) {
    int c = i * 16 + cc;
    float4 v = *(const float4*)(src + (size_t)(c0 + c) * Dh + d4);
    tile[d4 + 0][c] = f2bf(v.x);
    tile[d4 + 1][c] = f2bf(v.y);
    tile[d4 + 2][c] = f2bf(v.z);
    tile[d4 + 3][c] = f2bf(v.w);
  }
  __syncthreads();
  const int c4 = (tid & 15) * 4, dd = tid >> 4;
#pragma unroll
  for (int i = 0; i < 4; ++i) {
    int d = i * 16 + dd;
    ushort4 o;
    o.x = tile[d][c4]; o.y = tile[d][c4 + 1];
    o.z = tile[d][c4 + 2]; o.w = tile[d][c4 + 3];
    *(ushort4*)(wt + (size_t)(mh * 64 + d) * Cdim + c0 + c4) = o;
  }
}

// QKV GEMM, 2-phase dbuf: 128x128, BK=32. Q pre-scaled by 1/32*log2e.
__global__ __launch_bounds__(256) void k_gemm_qkv(const u16* __restrict__ xb,
                                                  const u16* __restrict__ wt,
                                                  u16* __restrict__ qb,
                                                  u16* __restrict__ kb,
                                                  u16* __restrict__ vtb) {
  __shared__ __align__(16) u16 As[2][4096], Bs[2][4096];
  const int tid = threadIdx.x, lane = tid & 63, wid = tid >> 6;
  const int cl = lane & 15, kg = lane >> 4;
  const int row0 = blockIdx.y * 128, col0 = blockIdx.x * 128;
  const int wrow = (wid >> 1) * 64, wcol = (wid & 1) * 64;
  f32x4 acc[4][4] = {};
  const u16* a_src = xb + (size_t)(row0 + 32 * wid + (lane >> 2)) * Cdim + (lane & 3) * 8;
  const u16* b_src = wt + (size_t)(col0 + 32 * wid + (lane >> 2)) * Cdim + (lane & 3) * 8;

  auto stage = [&](int buf, int ke) {
    u16* Ad = &As[buf][1024 * wid];
    u16* Bd = &Bs[buf][1024 * wid];
    GLD16(a_src + ke, Ad);
    GLD16(a_src + 16 * Cdim + ke, Ad + 512);
    GLD16(b_src + ke, Bd);
    GLD16(b_src + 16 * Cdim + ke, Bd + 512);
  };

  stage(0, 0);
  __syncthreads();
  int cur = 0;
  for (int kk = 0; kk < 32; ++kk) {
    if (kk < 31) stage(cur ^ 1, (kk + 1) * 32);
    const u16* ar = &As[cur][(wrow + cl) * 32 + kg * 8];
    const u16* br = &Bs[cur][(wcol + cl) * 32 + kg * 8];
    bf16x8 af[4], bfr[4];
#pragma unroll
    for (int mi = 0; mi < 4; ++mi) af[mi] = *(const bf16x8*)(ar + mi * 512);
#pragma unroll
    for (int ni = 0; ni < 4; ++ni) bfr[ni] = *(const bf16x8*)(br + ni * 512);
#pragma unroll
    for (int mi = 0; mi < 4; ++mi)
#pragma unroll
      for (int ni = 0; ni < 4; ++ni)
        acc[mi][ni] = MFMA(af[mi], bfr[ni], acc[mi][ni]);
    __syncthreads();
    cur ^= 1;
  }
#pragma unroll
  for (int mi = 0; mi < 4; ++mi) {
#pragma unroll
    for (int ni = 0; ni < 4; ++ni) {
      int n = col0 + wcol + ni * 16 + cl;
      int m = n >> 10, h = (n >> 6) & 15, d = n & 63;
#pragma unroll
      for (int j = 0; j < 4; ++j) {
        int r = row0 + wrow + mi * 16 + kg * 4 + j;
        int b = r >> 11, t = r & 2047;
        float av = acc[mi][ni][j];
        if (m == 0) av *= 0.04508422f;  // 1/sqrt(C) * log2(e)
        u16 v = f2bf(av);
        size_t bh = (size_t)(b * Hn + h);
        if (m == 0)
          qb[(bh * Tsz + t) * Dh + d] = v;
        else if (m == 1)
          kb[(bh * Tsz + t) * Dh + d] = v;
        else
          vtb[(bh * Dh + d) * Tsz + t] = v;
      }
    }
  }
}

// ---- split-KV flash attention ----
// Grid 2048 flat: xcd=bid&7, idx=bid>>3; p=xcd+8*(idx>>6); rem=idx&63;
// t=31-(rem>>1) (longest first), half=rem&1. Block = 4 waves, wave owns 16
// q-rows of tile t, processes kv tiles [kt0,kt1). Writes unnormalized f16
// partial O (scaled 2^-8) + per-row (m+8, l*2^-8) f32.
// launch_bounds (256,4): VGPR cap 128 -> no spills (R8's (256,8) capped at 64
// and spilled ~1.2 GB to scratch).
__global__ __launch_bounds__(256, 4) void k_attn(const u16* __restrict__ qb,
                                                 const u16* __restrict__ kb,
                                                 const u16* __restrict__ vtb,
                                                 f16* __restrict__ pO0,
                                                 f16* pO1,
                                                 float2* __restrict__ ml0,
                                                 float2* __restrict__ ml1) {
  __shared__ __align__(16) u16 Plds[4][1024];
  const int lane = threadIdx.x & 63, wid = threadIdx.x >> 6;
  const int cl = lane & 15, kg = lane >> 4;
  const int xcd = blockIdx.x & 7, idx = blockIdx.x >> 3;
  const int p = xcd + 8 * (idx >> 6);
  const int rem = idx & 63;
  const int t = 31 - (rem >> 1);
  const int half = rem & 1;
  const int h = p & 15, b = p >> 4;
  const int n = t + 1, h0n = (n + 1) >> 1;
  const int kt0 = half ? h0n : 0;
  const int kt1 = half ? n : h0n;
  const int qr = t * 64 + wid * 16;
  const size_t bh = (size_t)(b * Hn + h);
  const u16* Qp = qb + bh * Tsz * Dh;
  const u16* Kp = kb + bh * Tsz * Dh;
  const u16* Vp = vtb + bh * Dh * Tsz;

  bf16x8 qa0 = *(const bf16x8*)(Qp + (size_t)(qr + cl) * Dh + kg * 8);
  bf16x8 qa1 = *(const bf16x8*)(Qp + (size_t)(qr + cl) * Dh + 32 + kg * 8);

  f32x4 o[4] = {};
  float m = NEGINF, l = 0.f;

  char* pb = (char*)&Plds[wid][0];
  const int rdoff0 = ((cl << 7) + (kg << 4)) ^ ((cl & 7) << 4);
  const int rdoff1 = ((cl << 7) + 64 + (kg << 4)) ^ ((cl & 7) << 4);
  const int rowoff = wid * 16;

  for (int kt = kt0; kt < kt1; ++kt) {
    const int k0 = kt * 64;
    bf16x8 kf[8];
#pragma unroll
    for (int nt = 0; nt < 4; ++nt) {
      const u16* kp = Kp + (size_t)(k0 + nt * 16 + cl) * Dh + kg * 8;
      kf[nt * 2] = *(const bf16x8*)kp;
      kf[nt * 2 + 1] = *(const bf16x8*)(kp + 32);
    }
    f32x4 sv[4];
    __builtin_amdgcn_s_setprio(1);
#pragma unroll
    for (int nt = 0; nt < 4; ++nt) {
      f32x4 z = {};
      z = MFMA(kf[nt * 2], qa0, z);
      z = MFMA(kf[nt * 2 + 1], qa1, z);
      sv[nt] = z;
    }
    __builtin_amdgcn_s_setprio(0);
    // V load after QK: kf dead -> register reuse; latency hidden by softmax
    bf16x8 vf[8];
#pragma unroll
    for (int dt = 0; dt < 4; ++dt) {
      const u16* vp = Vp + (size_t)(dt * 16 + cl) * Tsz + k0 + kg * 8;
      vf[dt * 2] = *(const bf16x8*)vp;
      vf[dt * 2 + 1] = *(const bf16x8*)(vp + 32);
    }
    if (kt == t) {  // diag tile mask
#pragma unroll
      for (int nt = 0; nt < 4; ++nt)
#pragma unroll
        for (int j = 0; j < 4; ++j)
          if (nt * 16 + kg * 4 + j > rowoff + cl) sv[nt][j] = NEGINF;
    }
    float tm = fmaxf(fmaxf(fmaxf(sv[0][0], sv[0][1]), fmaxf(sv[0][2], sv[0][3])),
                     fmaxf(fmaxf(sv[1][0], sv[1][1]), fmaxf(sv[1][2], sv[1][3])));
    tm = fmaxf(tm, fmaxf(fmaxf(fmaxf(sv[2][0], sv[2][1]), fmaxf(sv[2][2], sv[2][3])),
                         fmaxf(fmaxf(sv[3][0], sv[3][1]), fmaxf(sv[3][2], sv[3][3]))));
    if (!__all(tm <= m + 8.0f)) {
      tm = fmaxf(tm, __shfl_xor(tm, 16));
      tm = fmaxf(tm, __shfl_xor(tm, 32));
      float mnew = fmaxf(m, tm);
      float corr = EXP2(m - mnew);
      m = mnew;
      l *= corr;
      float c0 = __shfl(corr, kg * 4 + 0);
      float c1 = __shfl(corr, kg * 4 + 1);
      float c2 = __shfl(corr, kg * 4 + 2);
      float c3 = __shfl(corr, kg * 4 + 3);
#pragma unroll
      for (int dt = 0; dt < 4; ++dt) {
        o[dt][0] *= c0; o[dt][1] *= c1; o[dt][2] *= c2; o[dt][3] *= c3;
      }
    }
    float rs = 0.f;
#pragma unroll
    for (int nt = 0; nt < 4; ++nt)
#pragma unroll
      for (int j = 0; j < 4; ++j) {
        float pv = EXP2(sv[nt][j] - m);
        sv[nt][j] = pv;
        rs += pv;
      }
    l += rs;
#pragma unroll
    for (int nt = 0; nt < 4; ++nt) {
      uint2 pk;
      pk.x = cvtpk(sv[nt][0], sv[nt][1]);
      pk.y = cvtpk(sv[nt][2], sv[nt][3]);
      int waddr = ((cl << 7) + (nt << 5) + (kg << 3)) ^ ((cl & 7) << 4);
      *(uint2*)(pb + waddr) = pk;
    }
    bf16x8 pa0 = *(const bf16x8*)(pb + rdoff0);
    bf16x8 pa1 = *(const bf16x8*)(pb + rdoff1);
    __builtin_amdgcn_s_setprio(1);
#pragma unroll
    for (int dt = 0; dt < 4; ++dt) {
      o[dt] = MFMA(pa0, vf[dt * 2], o[dt]);
      o[dt] = MFMA(pa1, vf[dt * 2 + 1], o[dt]);
    }
    __builtin_amdgcn_s_setprio(0);
  }

  // finish lazy l reduction (sum over kg duplicates)
  l += __shfl_xor(l, 16);
  l += __shfl_xor(l, 32);
  // write partials: O*2^-8 as f16, (m+8, l*2^-8) as f32 (defer-safe range)
  f16* po = half ? pO1 : pO0;
#pragma unroll
  for (int dt = 0; dt < 4; ++dt)
#pragma unroll
    for (int j = 0; j < 4; ++j) {
      int tr = qr + kg * 4 + j;
      po[(size_t)(b * Tsz + tr) * Cdim + h * Dh + dt * 16 + cl] =
          (f16)(o[dt][j] * 0.00390625f);
    }
  if (lane < 16) {
    float2* ml = half ? ml1 : ml0;
    ml[(size_t)(b * Hn + h) * Tsz + qr + lane] = make_float2(m + 8.0f, l * 0.00390625f);
  }
}

// Combine: per q-row merge the two halves, normalize, write bf16 ob (in-place
// over pO1). 262144 threads, 16 elems each.
__global__ __launch_bounds__(256) void k_combine(const f16* __restrict__ pO0,
                                                 const f16* pO1,
                                                 const float2* __restrict__ ml0,
                                                 const float2* __restrict__ ml1,
                                                 u16* ob) {
  int g = blockIdx.x * 256 + threadIdx.x;  // 0..262143
  int q = g & 3, h = (g >> 2) & 15;
  int row = g >> 6;                        // b*2048 + trow
  int b = row >> 11, trow = row & 2047;
  size_t mli = (size_t)(b * Hn + h) * Tsz + trow;
  float2 v0 = ml0[mli], v1 = ml1[mli];
  float M = fmaxf(v0.x, v1.x);
  float w0 = exp2f(v0.x - M), w1 = exp2f(v1.x - M);
  float inv = 1.0f / (v0.y * w0 + v1.y * w1);
  w0 *= inv; w1 *= inv;
  size_t off = (size_t)row * Cdim + h * 64 + q * 16;
  f16x8v a0 = *(const f16x8v*)(pO0 + off);
  f16x8v a1 = *(const f16x8v*)(pO0 + off + 8);
  f16x8v b0 = *(const f16x8v*)(pO1 + off);
  f16x8v b1 = *(const f16x8v*)(pO1 + off + 8);
  ushort4 r0, r1, r2, r3;
  r0.x = f2bf((float)a0[0] * w0 + (float)b0[0] * w1);
  r0.y = f2bf((float)a0[1] * w0 + (float)b0[1] * w1);
  r0.z = f2bf((float)a0[2] * w0 + (float)b0[2] * w1);
  r0.w = f2bf((float)a0[3] * w0 + (float)b0[3] * w1);
  r1.x = f2bf((float)a0[4] * w0 + (float)b0[4] * w1);
  r1.y = f2bf((float)a0[5] * w0 + (float)b0[5] * w1);
  r1.z = f2bf((float)a0[6] * w0 + (float)b0[6] * w1);
  r1.w = f2bf((float)a0[7] * w0 + (float)b0[7] * w1);
  r2.x = f2bf((float)a1[0] * w0 + (float)b1[0] * w1);
  r2.y = f2bf((float)a1[1] * w0 + (float)b1[1] * w1);
  r2.z = f2bf((float)a1[2] * w0 + (float)b1[2] * w1);
  r2.w = f2bf((float)a1[3] * w0 + (float)b1[3] * w1);
  r3.x = f2bf((float)a1[4] * w0 + (float)b1[4] * w1);
  r3.y = f2bf((float)a1[5] * w0 + (float)b1[5] * w1);
  r3.z = f2bf((float)a1[6] * w0 + (float)b1[6] * w1);
  r3.w = f2bf((float)a1[7] * w0 + (float)b1[7] * w1);
  *(ushort4*)(ob + off) = r0;
  *(ushort4*)(ob + off + 4) = r1;
  *(ushort4*)(ob + off + 8) = r2;
  *(ushort4*)(ob + off + 12) = r3;
}

// Out GEMM, 2-phase dbuf: 128x64 tile, BK=32.
__global__ __launch_bounds__(256) void k_gemm_out(const u16* __restrict__ ob,
                                                  const u16* __restrict__ wob,
                                                  const float* __restrict__ bo,
                                                  float* __restrict__ out) {
  __shared__ __align__(16) u16 As[2][4096], Bs[2][2048];
  const int tid = threadIdx.x, lane = tid & 63, wid = tid >> 6;
  const int cl = lane & 15, kg = lane >> 4;
  const int row0 = blockIdx.y * 128, col0 = blockIdx.x * 64;
  const int wrow = (wid >> 1) * 64, wcol = (wid & 1) * 32;
  f32x4 acc[4][2] = {};
  const u16* a_src = ob + (size_t)(row0 + 32 * wid + (lane >> 2)) * Cdim + (lane & 3) * 8;
  const u16* b_src = wob + (size_t)(col0 + 16 * wid + (lane >> 2)) * Cdim + (lane & 3) * 8;

  auto stage = [&](int buf, int ke) {
    u16* Ad = &As[buf][1024 * wid];
    u16* Bd = &Bs[buf][512 * wid];
    GLD16(a_src + ke, Ad);
    GLD16(a_src + 16 * Cdim + ke, Ad + 512);
    GLD16(b_src + ke, Bd);
  };

  stage(0, 0);
  __syncthreads();
  int cur = 0;
  for (int kk = 0; kk < 32; ++kk) {
    if (kk < 31) stage(cur ^ 1, (kk + 1) * 32);
    const u16* ar = &As[cur][(wrow + cl) * 32 + kg * 8];
    const u16* br = &Bs[cur][(wcol + cl) * 32 + kg * 8];
    bf16x8 af[4], bfr[2];
#pragma unroll
    for (int mi = 0; mi < 4; ++mi) af[mi] = *(const bf16x8*)(ar + mi * 512);
#pragma unroll
    for (int ni = 0; ni < 2; ++ni) bfr[ni] = *(const bf16x8*)(br + ni * 512);
#pragma unroll
    for (int mi = 0; mi < 4; ++mi)
#pragma unroll
      for (int ni = 0; ni < 2; ++ni)
        acc[mi][ni] = MFMA(af[mi], bfr[ni], acc[mi][ni]);
    __syncthreads();
    cur ^= 1;
  }
#pragma unroll
  for (int mi = 0; mi < 4; ++mi) {
#pragma unroll
    for (int ni = 0; ni < 2; ++ni) {
      int n = col0 + wcol + ni * 16 + cl;
      float bias = bo[n];
#pragma unroll
      for (int j = 0; j < 4; ++j) {
        int r = row0 + wrow + mi * 16 + kg * 4 + j;
        out[(size_t)r * Cdim + n] = acc[mi][ni][j] + bias;
      }
    }
  }
}

extern "C" void kernel_launch(void* const* d_in, const int* in_sizes, int n_in,
                              void* d_out, int out_size, void* d_ws, size_t ws_size,
                              hipStream_t stream) {
  (void)in_sizes; (void)n_in; (void)out_size; (void)ws_size;
  const float* x = (const float*)d_in[0];
  const float* Wq = (const float*)d_in[1];
  const float* Wk = (const float*)d_in[2];
  const float* Wv = (const float*)d_in[3];
  const float* Wo = (const float*)d_in[4];
  const float* bo = (const float*)d_in[5];
  float* out = (float*)d_out;
  char* ws = (char*)d_ws;
  u16* xb = (u16*)(ws);                  // 8 MiB  x bf16 (dead after qkv gemm)
  u16* wt = (u16*)(ws + (8u << 20));     // 6 MiB  Wqkv^T (dead after qkv gemm)
  u16* wob = (u16*)(ws + (14u << 20));   // 2 MiB  Wo bf16
  u16* qb = (u16*)(ws + (16u << 20));    // 8 MiB  Q (pre-scaled)
  u16* kb = (u16*)(ws + (24u << 20));    // 8 MiB  K
  u16* vtb = (u16*)(ws + (32u << 20));   // 8 MiB  V^T
  u16* ob = (u16*)(ws + (40u << 20));    // 8 MiB  attn out bf16 (also pO1)
  // attn partials reuse dead xb/wt region:
  f16* pO0 = (f16*)(ws);                       // 8 MiB  [0, 8.39MB)
  float2* ml0 = (float2*)(ws + (17u << 19));   // 0.5 MiB @ 8.5 MiB
  float2* ml1 = (float2*)(ws + (19u << 19));   // 0.5 MiB @ 9.5 MiB
  f16* pO1 = (f16*)(ws + (40u << 20));         // in-place over ob

  k_cast_x<<<4096, 256, 0, stream>>>(x, xb, Bsz * Tsz * Cdim / 4);
  k_cast_x<<<1024, 256, 0, stream>>>(Wo, wob, Cdim * Cdim / 4);
  k_cast_w<<<dim3(16, 48), 256, 0, stream>>>(Wq, Wk, Wv, wt);
  k_gemm_qkv<<<dim3(24, 32), 256, 0, stream>>>(xb, wt, qb, kb, vtb);
  k_attn<<<2048, 256, 0, stream>>>(qb, kb, vtb, pO0, pO1, ml0, ml1);
  k_combine<<<1024, 256, 0, stream>>>(pO0, pO1, ml0, ml1, ob);
  k_gemm_out<<<dim3(16, 32), 256, 0, stream>>>(ob, wob, bo, out);
}

// Round 10
// 123.345 us; speedup vs baseline: 3.7743x; 1.9077x over previous
//
#include <hip/hip_runtime.h>

// MHA forward: B=2 T=2048 C=1024 H=16 D=64, causal, scale 1/sqrt(C)=1/32
// cast -> QKV gemm (2-phase dbuf) -> folded flash attn (dual rowset/wave,
// block-shared double-buffered LDS K/V via global_load_lds + XOR swizzle,
// swapped QK^T, native exp2, defer-max, XCD clustering) -> out gemm

#define Bsz 2
#define Tsz 2048
#define Cdim 1024
#define Hn 16
#define Dh 64

typedef short bf16x8 __attribute__((ext_vector_type(8)));
typedef float f32x4 __attribute__((ext_vector_type(4)));
typedef unsigned short u16;

#define MFMA(a, b, c) __builtin_amdgcn_mfma_f32_16x16x32_bf16(a, b, c, 0, 0, 0)
#define NEGINF (-__builtin_inff())
#define EXP2(x) __builtin_amdgcn_exp2f(x)

#define GLD16(g, l)                                                            \
  __builtin_amdgcn_global_load_lds((const __attribute__((address_space(1))) void*)(g), \
                                   (__attribute__((address_space(3))) void*)(l), 16, 0, 0)

__device__ __forceinline__ u16 f2bf(float f) {
  unsigned u = __builtin_bit_cast(unsigned, f);
  unsigned r = 0x7fffu + ((u >> 16) & 1u);
  return (u16)((u + r) >> 16);
}

__device__ __forceinline__ unsigned cvtpk(float lo, float hi) {
  unsigned r;
  asm("v_cvt_pk_bf16_f32 %0, %1, %2" : "=v"(r) : "v"(lo), "v"(hi));
  return r;
}

// flat f32 -> bf16 cast, 4 elems/thread
__global__ __launch_bounds__(256) void k_cast_x(const float* __restrict__ x,
                                                u16* __restrict__ xb, int n4) {
  int i = blockIdx.x * 256 + threadIdx.x;
  if (i >= n4) return;
  float4 v = reinterpret_cast<const float4*>(x)[i];
  ushort4 o;
  o.x = f2bf(v.x); o.y = f2bf(v.y); o.z = f2bf(v.z); o.w = f2bf(v.w);
  reinterpret_cast<ushort4*>(xb)[i] = o;
}

// Wq/Wk/Wv [H][C][D] f32 -> wt [(m*H+h)*D+d][C] bf16 via LDS tile transpose.
__global__ __launch_bounds__(256) void k_cast_w(const float* __restrict__ Wq,
                                                const float* __restrict__ Wk,
                                                const float* __restrict__ Wv,
                                                u16* __restrict__ wt) {
  __shared__ u16 tile[64][68];
  const int mh = blockIdx.y;
  const int m = mh >> 4, h = mh & 15;
  const float* src = (m == 0 ? Wq : m == 1 ? Wk : Wv) + (size_t)h * Cdim * Dh;
  const int c0 = blockIdx.x * 64;
  const int tid = threadIdx.x;
  const int cc = tid >> 4, d4 = (tid & 15) * 4;
#pragma unroll
  for (int i = 0; i < 4; ++i) {
    int c = i * 16 + cc;
    float4 v = *(const float4*)(src + (size_t)(c0 + c) * Dh + d4);
    tile[d4 + 0][c] = f2bf(v.x);
    tile[d4 + 1][c] = f2bf(v.y);
    tile[d4 + 2][c] = f2bf(v.z);
    tile[d4 + 3][c] = f2bf(v.w);
  }
  __syncthreads();
  const int c4 = (tid & 15) * 4, dd = tid >> 4;
#pragma unroll
  for (int i = 0; i < 4; ++i) {
    int d = i * 16 + dd;
    ushort4 o;
    o.x = tile[d][c4]; o.y = tile[d][c4 + 1];
    o.z = tile[d][c4 + 2]; o.w = tile[d][c4 + 3];
    *(ushort4*)(wt + (size_t)(mh * 64 + d) * Cdim + c0 + c4) = o;
  }
}

// QKV GEMM, 2-phase dbuf: 128x128, BK=32. Q pre-scaled by 1/32*log2e.
__global__ __launch_bounds__(256) void k_gemm_qkv(const u16* __restrict__ xb,
                                                  const u16* __restrict__ wt,
                                                  u16* __restrict__ qb,
                                                  u16* __restrict__ kb,
                                                  u16* __restrict__ vtb) {
  __shared__ __align__(16) u16 As[2][4096], Bs[2][4096];
  const int tid = threadIdx.x, lane = tid & 63, wid = tid >> 6;
  const int cl = lane & 15, kg = lane >> 4;
  const int row0 = blockIdx.y * 128, col0 = blockIdx.x * 128;
  const int wrow = (wid >> 1) * 64, wcol = (wid & 1) * 64;
  f32x4 acc[4][4] = {};
  const u16* a_src = xb + (size_t)(row0 + 32 * wid + (lane >> 2)) * Cdim + (lane & 3) * 8;
  const u16* b_src = wt + (size_t)(col0 + 32 * wid + (lane >> 2)) * Cdim + (lane & 3) * 8;

  auto stage = [&](int buf, int ke) {
    u16* Ad = &As[buf][1024 * wid];
    u16* Bd = &Bs[buf][1024 * wid];
    GLD16(a_src + ke, Ad);
    GLD16(a_src + 16 * Cdim + ke, Ad + 512);
    GLD16(b_src + ke, Bd);
    GLD16(b_src + 16 * Cdim + ke, Bd + 512);
  };

  stage(0, 0);
  __syncthreads();
  int cur = 0;
  for (int kk = 0; kk < 32; ++kk) {
    if (kk < 31) stage(cur ^ 1, (kk + 1) * 32);
    const u16* ar = &As[cur][(wrow + cl) * 32 + kg * 8];
    const u16* br = &Bs[cur][(wcol + cl) * 32 + kg * 8];
    bf16x8 af[4], bfr[4];
#pragma unroll
    for (int mi = 0; mi < 4; ++mi) af[mi] = *(const bf16x8*)(ar + mi * 512);
#pragma unroll
    for (int ni = 0; ni < 4; ++ni) bfr[ni] = *(const bf16x8*)(br + ni * 512);
#pragma unroll
    for (int mi = 0; mi < 4; ++mi)
#pragma unroll
      for (int ni = 0; ni < 4; ++ni)
        acc[mi][ni] = MFMA(af[mi], bfr[ni], acc[mi][ni]);
    __syncthreads();
    cur ^= 1;
  }
#pragma unroll
  for (int mi = 0; mi < 4; ++mi) {
#pragma unroll
    for (int ni = 0; ni < 4; ++ni) {
      int n = col0 + wcol + ni * 16 + cl;
      int m = n >> 10, h = (n >> 6) & 15, d = n & 63;
#pragma unroll
      for (int j = 0; j < 4; ++j) {
        int r = row0 + wrow + mi * 16 + kg * 4 + j;
        int b = r >> 11, t = r & 2047;
        float av = acc[mi][ni][j];
        if (m == 0) av *= 0.04508422f;  // 1/sqrt(C) * log2(e)
        u16 v = f2bf(av);
        size_t bh = (size_t)(b * Hn + h);
        if (m == 0)
          qb[(bh * Tsz + t) * Dh + d] = v;
        else if (m == 1)
          kb[(bh * Tsz + t) * Dh + d] = v;
        else
          vtb[(bh * Dh + d) * Tsz + t] = v;
      }
    }
  }
}

// ---- folded flash attention with block-shared double-buffered LDS K/V ----
// Block handles q-tile pair (tp, 31-tp); 4 waves, each wave = dual 16-row
// rowsets. K[64][64] + V^T[64][64] staged per tile into LDS (16KB) via
// global_load_lds(16B), double-buffered one tile ahead. LDS image is linear;
// bank conflicts fixed by inverse-swizzling the GLOBAL source address and
// XOR-swizzling the ds_read address (byte ^= ((row&7)<<4); rule #21).
__global__ __launch_bounds__(256, 2) void k_attn(const u16* __restrict__ qb,
                                                 const u16* __restrict__ kb,
                                                 const u16* __restrict__ vtb,
                                                 u16* __restrict__ ob) {
  __shared__ __align__(16) u16 KV[2][8192];      // [buf][ K: 0..4095 | V: 4096..8191 ]
  __shared__ __align__(16) u16 Plds[4][2][1024]; // per-wave P roundtrip
  const int lane = threadIdx.x & 63, wid = threadIdx.x >> 6;
  const int cl = lane & 15, kg = lane >> 4;
  const int bid = blockIdx.x;
  const int kdec = bid >> 3;
  const int p = (bid & 7) + ((kdec >> 4) << 3);  // XCD clustering: bid&7 = XCD
  const int tp = kdec & 15;
  const int h = p & 15, b = p >> 4;
  const int tA = tp, tB = 31 - tp;
  const int qrA = tA * 64 + wid * 16;
  const int qrB = tB * 64 + wid * 16;
  const size_t bh = (size_t)(b * Hn + h);
  const u16* Qp = qb + bh * Tsz * Dh;
  const u16* Kp = kb + bh * Tsz * Dh;
  const u16* Vp = vtb + bh * Dh * Tsz;

  // staging sources: thread covers 4 x 16B chunks per tile (2 K, 2 V).
  // linear LDS byte offset lo = c*4096 + wid*1024 + lane*16; row r = lo/128,
  // col byte cb = lo%128; source col is swizzled: cbs = cb ^ ((r&7)<<4).
  const u16* pk_src[2];
  const u16* pv_src[2];
#pragma unroll
  for (int c = 0; c < 2; ++c) {
    int lo = c * 4096 + wid * 1024 + lane * 16;
    int r = lo >> 7, cb = lo & 127;
    int cbs = cb ^ ((r & 7) << 4);
    pk_src[c] = Kp + r * Dh + (cbs >> 1);               // + kt*4096 at runtime
    pv_src[c] = Vp + (size_t)r * Tsz + (cbs >> 1);      // + kt*64   at runtime
  }

  auto stage = [&](int buf, int kt) {
    GLD16(pk_src[0] + kt * 4096, &KV[buf][(wid * 1024) >> 1]);
    GLD16(pk_src[1] + kt * 4096, &KV[buf][(4096 + wid * 1024) >> 1]);
    GLD16(pv_src[0] + kt * 64, &KV[buf][(8192 + wid * 1024) >> 1]);
    GLD16(pv_src[1] + kt * 64, &KV[buf][(12288 + wid * 1024) >> 1]);
  };

  bf16x8 qaA0 = *(const bf16x8*)(Qp + (size_t)(qrA + cl) * Dh + kg * 8);
  bf16x8 qaA1 = *(const bf16x8*)(Qp + (size_t)(qrA + cl) * Dh + 32 + kg * 8);
  bf16x8 qaB0 = *(const bf16x8*)(Qp + (size_t)(qrB + cl) * Dh + kg * 8);
  bf16x8 qaB1 = *(const bf16x8*)(Qp + (size_t)(qrB + cl) * Dh + 32 + kg * 8);

  f32x4 oA[4] = {}, oB[4] = {};
  float mA = NEGINF, lA = 0.f, mB = NEGINF, lB = 0.f;

  char* pbA = (char*)&Plds[wid][0][0];
  char* pbB = (char*)&Plds[wid][1][0];
  const int rdoff0 = ((cl << 7) + (kg << 4)) ^ ((cl & 7) << 4);
  const int rdoff1 = ((cl << 7) + 64 + (kg << 4)) ^ ((cl & 7) << 4);
  const int rowoff = wid * 16;
  // frag-read swizzled column offsets (row low bits = cl&7 for both K and V)
  const int swz0 = (kg * 16) ^ ((cl & 7) << 4);
  const int swz1 = (kg * 16 + 64) ^ ((cl & 7) << 4);

  // softmax + P roundtrip + PV, one rowset
  auto sm_pv = [&](f32x4 s[4], float& m, float& l, f32x4 o[4],
                   const bf16x8 vf[8], char* pb, bool mask) {
    if (mask) {
#pragma unroll
      for (int nt = 0; nt < 4; ++nt)
#pragma unroll
        for (int j = 0; j < 4; ++j)
          if (nt * 16 + kg * 4 + j > rowoff + cl) s[nt][j] = NEGINF;
    }
    float tm = fmaxf(fmaxf(fmaxf(s[0][0], s[0][1]), fmaxf(s[0][2], s[0][3])),
                     fmaxf(fmaxf(s[1][0], s[1][1]), fmaxf(s[1][2], s[1][3])));
    tm = fmaxf(tm, fmaxf(fmaxf(fmaxf(s[2][0], s[2][1]), fmaxf(s[2][2], s[2][3])),
                         fmaxf(fmaxf(s[3][0], s[3][1]), fmaxf(s[3][2], s[3][3]))));
    if (!__all(tm <= m + 8.0f)) {
      tm = fmaxf(tm, __shfl_xor(tm, 16));
      tm = fmaxf(tm, __shfl_xor(tm, 32));
      float mnew = fmaxf(m, tm);
      float corr = EXP2(m - mnew);
      m = mnew;
      l *= corr;
      float c0 = __shfl(corr, kg * 4 + 0);
      float c1 = __shfl(corr, kg * 4 + 1);
      float c2 = __shfl(corr, kg * 4 + 2);
      float c3 = __shfl(corr, kg * 4 + 3);
#pragma unroll
      for (int dt = 0; dt < 4; ++dt) {
        o[dt][0] *= c0; o[dt][1] *= c1; o[dt][2] *= c2; o[dt][3] *= c3;
      }
    }
    float rs = 0.f;
#pragma unroll
    for (int nt = 0; nt < 4; ++nt)
#pragma unroll
      for (int j = 0; j < 4; ++j) {
        float pv = EXP2(s[nt][j] - m);
        s[nt][j] = pv;
        rs += pv;
      }
    l += rs;
#pragma unroll
    for (int nt = 0; nt < 4; ++nt) {
      uint2 pk;
      pk.x = cvtpk(s[nt][0], s[nt][1]);
      pk.y = cvtpk(s[nt][2], s[nt][3]);
      int waddr = ((cl << 7) + (nt << 5) + (kg << 3)) ^ ((cl & 7) << 4);
      *(uint2*)(pb + waddr) = pk;
    }
    bf16x8 pa0 = *(const bf16x8*)(pb + rdoff0);
    bf16x8 pa1 = *(const bf16x8*)(pb + rdoff1);
    __builtin_amdgcn_s_setprio(1);
#pragma unroll
    for (int dt = 0; dt < 4; ++dt) {
      o[dt] = MFMA(pa0, vf[dt * 2], o[dt]);
      o[dt] = MFMA(pa1, vf[dt * 2 + 1], o[dt]);
    }
    __builtin_amdgcn_s_setprio(0);
  };

  const int ntot = tB + 1;
  stage(0, 0);
  __syncthreads();
  int cur = 0;
  for (int t = 0; t < ntot; ++t) {
    if (t + 1 < ntot) stage(cur ^ 1, t + 1);
    char* kvb = (char*)&KV[cur][0];
    // K frags from LDS (shared by both rowsets)
    bf16x8 ka[8];
#pragma unroll
    for (int nt = 0; nt < 4; ++nt) {
      int rbase = (nt * 16 + cl) << 7;
      ka[nt * 2] = *(const bf16x8*)(kvb + rbase + swz0);
      ka[nt * 2 + 1] = *(const bf16x8*)(kvb + rbase + swz1);
    }
    f32x4 sB[4];
    __builtin_amdgcn_s_setprio(1);
#pragma unroll
    for (int nt = 0; nt < 4; ++nt) {
      f32x4 z = {};
      z = MFMA(ka[nt * 2], qaB0, z);
      z = MFMA(ka[nt * 2 + 1], qaB1, z);
      sB[nt] = z;
    }
    __builtin_amdgcn_s_setprio(0);
    f32x4 sA[4];
    const bool actA = (t <= tA);
    if (actA) {
      __builtin_amdgcn_s_setprio(1);
#pragma unroll
      for (int nt = 0; nt < 4; ++nt) {
        f32x4 z = {};
        z = MFMA(ka[nt * 2], qaA0, z);
        z = MFMA(ka[nt * 2 + 1], qaA1, z);
        sA[nt] = z;
      }
      __builtin_amdgcn_s_setprio(0);
    }
    // V frags from LDS (shared by both rowsets)
    bf16x8 vf[8];
#pragma unroll
    for (int dt = 0; dt < 4; ++dt) {
      int rbase = 8192 + ((dt * 16 + cl) << 7);
      vf[dt * 2] = *(const bf16x8*)(kvb + rbase + swz0);
      vf[dt * 2 + 1] = *(const bf16x8*)(kvb + rbase + swz1);
    }
    if (actA) sm_pv(sA, mA, lA, oA, vf, pbA, t == tA);
    sm_pv(sB, mB, lB, oB, vf, pbB, t == tB);
    __syncthreads();  // drains next-tile gld_lds + protects buffer reuse
    cur ^= 1;
  }

  // epilogue: finish lazy l reduction, broadcast 1/l per O row
  lA += __shfl_xor(lA, 16); lA += __shfl_xor(lA, 32);
  lB += __shfl_xor(lB, 16); lB += __shfl_xor(lB, 32);
  float iA0 = 1.f / __shfl(lA, kg * 4 + 0), iA1 = 1.f / __shfl(lA, kg * 4 + 1);
  float iA2 = 1.f / __shfl(lA, kg * 4 + 2), iA3 = 1.f / __shfl(lA, kg * 4 + 3);
  float iB0 = 1.f / __shfl(lB, kg * 4 + 0), iB1 = 1.f / __shfl(lB, kg * 4 + 1);
  float iB2 = 1.f / __shfl(lB, kg * 4 + 2), iB3 = 1.f / __shfl(lB, kg * 4 + 3);
  float invA[4] = {iA0, iA1, iA2, iA3};
  float invB[4] = {iB0, iB1, iB2, iB3};
#pragma unroll
  for (int dt = 0; dt < 4; ++dt)
#pragma unroll
    for (int j = 0; j < 4; ++j) {
      int ta = qrA + kg * 4 + j;
      int tb = qrB + kg * 4 + j;
      ob[(size_t)(b * Tsz + ta) * Cdim + h * Dh + dt * 16 + cl] = f2bf(oA[dt][j] * invA[j]);
      ob[(size_t)(b * Tsz + tb) * Cdim + h * Dh + dt * 16 + cl] = f2bf(oB[dt][j] * invB[j]);
    }
}

// Out GEMM, 2-phase dbuf: 128x64 tile, BK=32.
__global__ __launch_bounds__(256) void k_gemm_out(const u16* __restrict__ ob,
                                                  const u16* __restrict__ wob,
                                                  const float* __restrict__ bo,
                                                  float* __restrict__ out) {
  __shared__ __align__(16) u16 As[2][4096], Bs[2][2048];
  const int tid = threadIdx.x, lane = tid & 63, wid = tid >> 6;
  const int cl = lane & 15, kg = lane >> 4;
  const int row0 = blockIdx.y * 128, col0 = blockIdx.x * 64;
  const int wrow = (wid >> 1) * 64, wcol = (wid & 1) * 32;
  f32x4 acc[4][2] = {};
  const u16* a_src = ob + (size_t)(row0 + 32 * wid + (lane >> 2)) * Cdim + (lane & 3) * 8;
  const u16* b_src = wob + (size_t)(col0 + 16 * wid + (lane >> 2)) * Cdim + (lane & 3) * 8;

  auto stage = [&](int buf, int ke) {
    u16* Ad = &As[buf][1024 * wid];
    u16* Bd = &Bs[buf][512 * wid];
    GLD16(a_src + ke, Ad);
    GLD16(a_src + 16 * Cdim + ke, Ad + 512);
    GLD16(b_src + ke, Bd);
  };

  stage(0, 0);
  __syncthreads();
  int cur = 0;
  for (int kk = 0; kk < 32; ++kk) {
    if (kk < 31) stage(cur ^ 1, (kk + 1) * 32);
    const u16* ar = &As[cur][(wrow + cl) * 32 + kg * 8];
    const u16* br = &Bs[cur][(wcol + cl) * 32 + kg * 8];
    bf16x8 af[4], bfr[2];
#pragma unroll
    for (int mi = 0; mi < 4; ++mi) af[mi] = *(const bf16x8*)(ar + mi * 512);
#pragma unroll
    for (int ni = 0; ni < 2; ++ni) bfr[ni] = *(const bf16x8*)(br + ni * 512);
#pragma unroll
    for (int mi = 0; mi < 4; ++mi)
#pragma unroll
      for (int ni = 0; ni < 2; ++ni)
        acc[mi][ni] = MFMA(af[mi], bfr[ni], acc[mi][ni]);
    __syncthreads();
    cur ^= 1;
  }
#pragma unroll
  for (int mi = 0; mi < 4; ++mi) {
#pragma unroll
    for (int ni = 0; ni < 2; ++ni) {
      int n = col0 + wcol + ni * 16 + cl;
      float bias = bo[n];
#pragma unroll
      for (int j = 0; j < 4; ++j) {
        int r = row0 + wrow + mi * 16 + kg * 4 + j;
        out[(size_t)r * Cdim + n] = acc[mi][ni][j] + bias;
      }
    }
  }
}

extern "C" void kernel_launch(void* const* d_in, const int* in_sizes, int n_in,
                              void* d_out, int out_size, void* d_ws, size_t ws_size,
                              hipStream_t stream) {
  (void)in_sizes; (void)n_in; (void)out_size; (void)ws_size;
  const float* x = (const float*)d_in[0];
  const float* Wq = (const float*)d_in[1];
  const float* Wk = (const float*)d_in[2];
  const float* Wv = (const float*)d_in[3];
  const float* Wo = (const float*)d_in[4];
  const float* bo = (const float*)d_in[5];
  float* out = (float*)d_out;
  char* ws = (char*)d_ws;
  u16* xb = (u16*)(ws);                  // 8 MiB  x bf16 [4096][1024]
  u16* wt = (u16*)(ws + (8u << 20));     // 6 MiB  Wqkv^T bf16 [3072][1024]
  u16* wob = (u16*)(ws + (14u << 20));   // 2 MiB  Wo bf16 [1024][1024]
  u16* qb = (u16*)(ws + (16u << 20));    // 8 MiB  Q (pre-scaled)
  u16* kb = (u16*)(ws + (24u << 20));    // 8 MiB  K
  u16* vtb = (u16*)(ws + (32u << 20));   // 8 MiB  V^T
  u16* ob = (u16*)(ws + (40u << 20));    // 8 MiB  attn out bf16

  k_cast_x<<<4096, 256, 0, stream>>>(x, xb, Bsz * Tsz * Cdim / 4);
  k_cast_x<<<1024, 256, 0, stream>>>(Wo, wob, Cdim * Cdim / 4);
  k_cast_w<<<dim3(16, 48), 256, 0, stream>>>(Wq, Wk, Wv, wt);
  k_gemm_qkv<<<dim3(24, 32), 256, 0, stream>>>(xb, wt, qb, kb, vtb);
  k_attn<<<512, 256, 0, stream>>>(qb, kb, vtb, ob);
  k_gemm_out<<<dim3(16, 32), 256, 0, stream>>>(ob, wob, bo, out);
}

// Round 11
// 122.596 us; speedup vs baseline: 3.7973x; 1.0061x over previous
//
#include <hip/hip_runtime.h>

// MHA forward: B=2 T=2048 C=1024 H=16 D=64, causal, scale 1/sqrt(C)=1/32
// cast -> QKV gemm (2-phase dbuf, chunk-swizzled LDS) -> folded flash attn
// (dual rowset/wave, LDS-staged dbuf K/V, swapped QK^T, exp2, defer-max,
// XCD clustering) -> out gemm (chunk-swizzled LDS)

#define Bsz 2
#define Tsz 2048
#define Cdim 1024
#define Hn 16
#define Dh 64

typedef short bf16x8 __attribute__((ext_vector_type(8)));
typedef float f32x4 __attribute__((ext_vector_type(4)));
typedef unsigned short u16;

#define MFMA(a, b, c) __builtin_amdgcn_mfma_f32_16x16x32_bf16(a, b, c, 0, 0, 0)
#define NEGINF (-__builtin_inff())
#define EXP2(x) __builtin_amdgcn_exp2f(x)

#define GLD16(g, l)                                                            \
  __builtin_amdgcn_global_load_lds((const __attribute__((address_space(1))) void*)(g), \
                                   (__attribute__((address_space(3))) void*)(l), 16, 0, 0)

__device__ __forceinline__ u16 f2bf(float f) {
  unsigned u = __builtin_bit_cast(unsigned, f);
  unsigned r = 0x7fffu + ((u >> 16) & 1u);
  return (u16)((u + r) >> 16);
}

__device__ __forceinline__ unsigned cvtpk(float lo, float hi) {
  unsigned r;
  asm("v_cvt_pk_bf16_f32 %0, %1, %2" : "=v"(r) : "v"(lo), "v"(hi));
  return r;
}

// flat f32 -> bf16 cast, 4 elems/thread
__global__ __launch_bounds__(256) void k_cast_x(const float* __restrict__ x,
                                                u16* __restrict__ xb, int n4) {
  int i = blockIdx.x * 256 + threadIdx.x;
  if (i >= n4) return;
  float4 v = reinterpret_cast<const float4*>(x)[i];
  ushort4 o;
  o.x = f2bf(v.x); o.y = f2bf(v.y); o.z = f2bf(v.z); o.w = f2bf(v.w);
  reinterpret_cast<ushort4*>(xb)[i] = o;
}

// Wq/Wk/Wv [H][C][D] f32 -> wt [(m*H+h)*D+d][C] bf16 via LDS tile transpose.
__global__ __launch_bounds__(256) void k_cast_w(const float* __restrict__ Wq,
                                                const float* __restrict__ Wk,
                                                const float* __restrict__ Wv,
                                                u16* __restrict__ wt) {
  __shared__ u16 tile[64][68];
  const int mh = blockIdx.y;
  const int m = mh >> 4, h = mh & 15;
  const float* src = (m == 0 ? Wq : m == 1 ? Wk : Wv) + (size_t)h * Cdim * Dh;
  const int c0 = blockIdx.x * 64;
  const int tid = threadIdx.x;
  const int cc = tid >> 4, d4 = (tid & 15) * 4;
#pragma unroll
  for (int i = 0; i < 4; ++i) {
    int c = i * 16 + cc;
    float4 v = *(const float4*)(src + (size_t)(c0 + c) * Dh + d4);
    tile[d4 + 0][c] = f2bf(v.x);
    tile[d4 + 1][c] = f2bf(v.y);
    tile[d4 + 2][c] = f2bf(v.z);
    tile[d4 + 3][c] = f2bf(v.w);
  }
  __syncthreads();
  const int c4 = (tid & 15) * 4, dd = tid >> 4;
#pragma unroll
  for (int i = 0; i < 4; ++i) {
    int d = i * 16 + dd;
    ushort4 o;
    o.x = tile[d][c4]; o.y = tile[d][c4 + 1];
    o.z = tile[d][c4 + 2]; o.w = tile[d][c4 + 3];
    *(ushort4*)(wt + (size_t)(mh * 64 + d) * Cdim + c0 + c4) = o;
  }
}

// QKV GEMM, 2-phase dbuf: 128x128, BK=32, chunk-swizzled LDS (rule #21:
// linear GLD-LDS dest + inverse-swizzled global source + swizzled ds_read;
// chunk ^= (row>>1)&3 -> each b128 phase = 2 lanes/bank, conflict-free).
__global__ __launch_bounds__(256) void k_gemm_qkv(const u16* __restrict__ xb,
                                                  const u16* __restrict__ wt,
                                                  u16* __restrict__ qb,
                                                  u16* __restrict__ kb,
                                                  u16* __restrict__ vtb) {
  __shared__ __align__(16) u16 As[2][4096], Bs[2][4096];
  const int tid = threadIdx.x, lane = tid & 63, wid = tid >> 6;
  const int cl = lane & 15, kg = lane >> 4;
  const int row0 = blockIdx.y * 128, col0 = blockIdx.x * 128;
  const int wrow = (wid >> 1) * 64, wcol = (wid & 1) * 64;
  f32x4 acc[4][4] = {};
  // staging source chunk pre-swizzled: c_src = (lane&3) ^ ((lane>>3)&3)
  const int csrc = ((lane & 3) ^ ((lane >> 3) & 3)) * 8;
  const u16* a_src = xb + (size_t)(row0 + 32 * wid + (lane >> 2)) * Cdim + csrc;
  const u16* b_src = wt + (size_t)(col0 + 32 * wid + (lane >> 2)) * Cdim + csrc;

  auto stage = [&](int buf, int ke) {
    u16* Ad = &As[buf][1024 * wid];
    u16* Bd = &Bs[buf][1024 * wid];
    GLD16(a_src + ke, Ad);
    GLD16(a_src + 16 * Cdim + ke, Ad + 512);
    GLD16(b_src + ke, Bd);
    GLD16(b_src + 16 * Cdim + ke, Bd + 512);
  };

  // ds_read chunk swizzle: kg ^ ((cl>>1)&3)  (row-base invariant)
  const int rdswz = (kg ^ ((cl >> 1) & 3)) * 8;

  stage(0, 0);
  __syncthreads();
  int cur = 0;
  for (int kk = 0; kk < 32; ++kk) {
    if (kk < 31) stage(cur ^ 1, (kk + 1) * 32);
    const u16* ar = &As[cur][(wrow + cl) * 32 + rdswz];
    const u16* br = &Bs[cur][(wcol + cl) * 32 + rdswz];
    bf16x8 af[4], bfr[4];
#pragma unroll
    for (int mi = 0; mi < 4; ++mi) af[mi] = *(const bf16x8*)(ar + mi * 512);
#pragma unroll
    for (int ni = 0; ni < 4; ++ni) bfr[ni] = *(const bf16x8*)(br + ni * 512);
#pragma unroll
    for (int mi = 0; mi < 4; ++mi)
#pragma unroll
      for (int ni = 0; ni < 4; ++ni)
        acc[mi][ni] = MFMA(af[mi], bfr[ni], acc[mi][ni]);
    __syncthreads();
    cur ^= 1;
  }
#pragma unroll
  for (int mi = 0; mi < 4; ++mi) {
#pragma unroll
    for (int ni = 0; ni < 4; ++ni) {
      int n = col0 + wcol + ni * 16 + cl;
      int m = n >> 10, h = (n >> 6) & 15, d = n & 63;
#pragma unroll
      for (int j = 0; j < 4; ++j) {
        int r = row0 + wrow + mi * 16 + kg * 4 + j;
        int b = r >> 11, t = r & 2047;
        float av = acc[mi][ni][j];
        if (m == 0) av *= 0.04508422f;  // 1/sqrt(C) * log2(e)
        u16 v = f2bf(av);
        size_t bh = (size_t)(b * Hn + h);
        if (m == 0)
          qb[(bh * Tsz + t) * Dh + d] = v;
        else if (m == 1)
          kb[(bh * Tsz + t) * Dh + d] = v;
        else
          vtb[(bh * Dh + d) * Tsz + t] = v;
      }
    }
  }
}

// ---- folded flash attention with block-shared double-buffered LDS K/V ----
__global__ __launch_bounds__(256, 2) void k_attn(const u16* __restrict__ qb,
                                                 const u16* __restrict__ kb,
                                                 const u16* __restrict__ vtb,
                                                 u16* __restrict__ ob) {
  __shared__ __align__(16) u16 KV[2][8192];      // [buf][ K: 0..4095 | V: 4096..8191 ]
  __shared__ __align__(16) u16 Plds[4][2][1024]; // per-wave P roundtrip
  const int lane = threadIdx.x & 63, wid = threadIdx.x >> 6;
  const int cl = lane & 15, kg = lane >> 4;
  const int bid = blockIdx.x;
  const int kdec = bid >> 3;
  const int p = (bid & 7) + ((kdec >> 4) << 3);  // XCD clustering
  const int tp = kdec & 15;
  const int h = p & 15, b = p >> 4;
  const int tA = tp, tB = 31 - tp;
  const int qrA = tA * 64 + wid * 16;
  const int qrB = tB * 64 + wid * 16;
  const size_t bh = (size_t)(b * Hn + h);
  const u16* Qp = qb + bh * Tsz * Dh;
  const u16* Kp = kb + bh * Tsz * Dh;
  const u16* Vp = vtb + bh * Dh * Tsz;

  const u16* pk_src[2];
  const u16* pv_src[2];
#pragma unroll
  for (int c = 0; c < 2; ++c) {
    int lo = c * 4096 + wid * 1024 + lane * 16;
    int r = lo >> 7, cb = lo & 127;
    int cbs = cb ^ ((r & 7) << 4);
    pk_src[c] = Kp + r * Dh + (cbs >> 1);
    pv_src[c] = Vp + (size_t)r * Tsz + (cbs >> 1);
  }

  auto stage = [&](int buf, int kt) {
    GLD16(pk_src[0] + kt * 4096, &KV[buf][(wid * 1024) >> 1]);
    GLD16(pk_src[1] + kt * 4096, &KV[buf][(4096 + wid * 1024) >> 1]);
    GLD16(pv_src[0] + kt * 64, &KV[buf][(8192 + wid * 1024) >> 1]);
    GLD16(pv_src[1] + kt * 64, &KV[buf][(12288 + wid * 1024) >> 1]);
  };

  bf16x8 qaA0 = *(const bf16x8*)(Qp + (size_t)(qrA + cl) * Dh + kg * 8);
  bf16x8 qaA1 = *(const bf16x8*)(Qp + (size_t)(qrA + cl) * Dh + 32 + kg * 8);
  bf16x8 qaB0 = *(const bf16x8*)(Qp + (size_t)(qrB + cl) * Dh + kg * 8);
  bf16x8 qaB1 = *(const bf16x8*)(Qp + (size_t)(qrB + cl) * Dh + 32 + kg * 8);

  f32x4 oA[4] = {}, oB[4] = {};
  float mA = NEGINF, lA = 0.f, mB = NEGINF, lB = 0.f;

  char* pbA = (char*)&Plds[wid][0][0];
  char* pbB = (char*)&Plds[wid][1][0];
  const int rdoff0 = ((cl << 7) + (kg << 4)) ^ ((cl & 7) << 4);
  const int rdoff1 = ((cl << 7) + 64 + (kg << 4)) ^ ((cl & 7) << 4);
  const int rowoff = wid * 16;
  const int swz0 = (kg * 16) ^ ((cl & 7) << 4);
  const int swz1 = (kg * 16 + 64) ^ ((cl & 7) << 4);

  auto sm_pv = [&](f32x4 s[4], float& m, float& l, f32x4 o[4],
                   const bf16x8 vf[8], char* pb, bool mask) {
    if (mask) {
#pragma unroll
      for (int nt = 0; nt < 4; ++nt)
#pragma unroll
        for (int j = 0; j < 4; ++j)
          if (nt * 16 + kg * 4 + j > rowoff + cl) s[nt][j] = NEGINF;
    }
    float tm = fmaxf(fmaxf(fmaxf(s[0][0], s[0][1]), fmaxf(s[0][2], s[0][3])),
                     fmaxf(fmaxf(s[1][0], s[1][1]), fmaxf(s[1][2], s[1][3])));
    tm = fmaxf(tm, fmaxf(fmaxf(fmaxf(s[2][0], s[2][1]), fmaxf(s[2][2], s[2][3])),
                         fmaxf(fmaxf(s[3][0], s[3][1]), fmaxf(s[3][2], s[3][3]))));
    if (!__all(tm <= m + 8.0f)) {
      tm = fmaxf(tm, __shfl_xor(tm, 16));
      tm = fmaxf(tm, __shfl_xor(tm, 32));
      float mnew = fmaxf(m, tm);
      float corr = EXP2(m - mnew);
      m = mnew;
      l *= corr;
      float c0 = __shfl(corr, kg * 4 + 0);
      float c1 = __shfl(corr, kg * 4 + 1);
      float c2 = __shfl(corr, kg * 4 + 2);
      float c3 = __shfl(corr, kg * 4 + 3);
#pragma unroll
      for (int dt = 0; dt < 4; ++dt) {
        o[dt][0] *= c0; o[dt][1] *= c1; o[dt][2] *= c2; o[dt][3] *= c3;
      }
    }
    float rs = 0.f;
#pragma unroll
    for (int nt = 0; nt < 4; ++nt)
#pragma unroll
      for (int j = 0; j < 4; ++j) {
        float pv = EXP2(s[nt][j] - m);
        s[nt][j] = pv;
        rs += pv;
      }
    l += rs;
#pragma unroll
    for (int nt = 0; nt < 4; ++nt) {
      uint2 pk;
      pk.x = cvtpk(s[nt][0], s[nt][1]);
      pk.y = cvtpk(s[nt][2], s[nt][3]);
      int waddr = ((cl << 7) + (nt << 5) + (kg << 3)) ^ ((cl & 7) << 4);
      *(uint2*)(pb + waddr) = pk;
    }
    bf16x8 pa0 = *(const bf16x8*)(pb + rdoff0);
    bf16x8 pa1 = *(const bf16x8*)(pb + rdoff1);
    __builtin_amdgcn_s_setprio(1);
#pragma unroll
    for (int dt = 0; dt < 4; ++dt) {
      o[dt] = MFMA(pa0, vf[dt * 2], o[dt]);
      o[dt] = MFMA(pa1, vf[dt * 2 + 1], o[dt]);
    }
    __builtin_amdgcn_s_setprio(0);
  };

  const int ntot = tB + 1;
  stage(0, 0);
  __syncthreads();
  int cur = 0;
  for (int t = 0; t < ntot; ++t) {
    if (t + 1 < ntot) stage(cur ^ 1, t + 1);
    char* kvb = (char*)&KV[cur][0];
    bf16x8 ka[8];
#pragma unroll
    for (int nt = 0; nt < 4; ++nt) {
      int rbase = (nt * 16 + cl) << 7;
      ka[nt * 2] = *(const bf16x8*)(kvb + rbase + swz0);
      ka[nt * 2 + 1] = *(const bf16x8*)(kvb + rbase + swz1);
    }
    f32x4 sB[4];
    __builtin_amdgcn_s_setprio(1);
#pragma unroll
    for (int nt = 0; nt < 4; ++nt) {
      f32x4 z = {};
      z = MFMA(ka[nt * 2], qaB0, z);
      z = MFMA(ka[nt * 2 + 1], qaB1, z);
      sB[nt] = z;
    }
    __builtin_amdgcn_s_setprio(0);
    f32x4 sA[4];
    const bool actA = (t <= tA);
    if (actA) {
      __builtin_amdgcn_s_setprio(1);
#pragma unroll
      for (int nt = 0; nt < 4; ++nt) {
        f32x4 z = {};
        z = MFMA(ka[nt * 2], qaA0, z);
        z = MFMA(ka[nt * 2 + 1], qaA1, z);
        sA[nt] = z;
      }
      __builtin_amdgcn_s_setprio(0);
    }
    bf16x8 vf[8];
#pragma unroll
    for (int dt = 0; dt < 4; ++dt) {
      int rbase = 8192 + ((dt * 16 + cl) << 7);
      vf[dt * 2] = *(const bf16x8*)(kvb + rbase + swz0);
      vf[dt * 2 + 1] = *(const bf16x8*)(kvb + rbase + swz1);
    }
    if (actA) sm_pv(sA, mA, lA, oA, vf, pbA, t == tA);
    sm_pv(sB, mB, lB, oB, vf, pbB, t == tB);
    __syncthreads();
    cur ^= 1;
  }

  lA += __shfl_xor(lA, 16); lA += __shfl_xor(lA, 32);
  lB += __shfl_xor(lB, 16); lB += __shfl_xor(lB, 32);
  float iA0 = 1.f / __shfl(lA, kg * 4 + 0), iA1 = 1.f / __shfl(lA, kg * 4 + 1);
  float iA2 = 1.f / __shfl(lA, kg * 4 + 2), iA3 = 1.f / __shfl(lA, kg * 4 + 3);
  float iB0 = 1.f / __shfl(lB, kg * 4 + 0), iB1 = 1.f / __shfl(lB, kg * 4 + 1);
  float iB2 = 1.f / __shfl(lB, kg * 4 + 2), iB3 = 1.f / __shfl(lB, kg * 4 + 3);
  float invA[4] = {iA0, iA1, iA2, iA3};
  float invB[4] = {iB0, iB1, iB2, iB3};
#pragma unroll
  for (int dt = 0; dt < 4; ++dt)
#pragma unroll
    for (int j = 0; j < 4; ++j) {
      int ta = qrA + kg * 4 + j;
      int tb = qrB + kg * 4 + j;
      ob[(size_t)(b * Tsz + ta) * Cdim + h * Dh + dt * 16 + cl] = f2bf(oA[dt][j] * invA[j]);
      ob[(size_t)(b * Tsz + tb) * Cdim + h * Dh + dt * 16 + cl] = f2bf(oB[dt][j] * invB[j]);
    }
}

// Out GEMM, 2-phase dbuf: 128x64 tile, BK=32, chunk-swizzled LDS.
__global__ __launch_bounds__(256) void k_gemm_out(const u16* __restrict__ ob,
                                                  const u16* __restrict__ wob,
                                                  const float* __restrict__ bo,
                                                  float* __restrict__ out) {
  __shared__ __align__(16) u16 As[2][4096], Bs[2][2048];
  const int tid = threadIdx.x, lane = tid & 63, wid = tid >> 6;
  const int cl = lane & 15, kg = lane >> 4;
  const int row0 = blockIdx.y * 128, col0 = blockIdx.x * 64;
  const int wrow = (wid >> 1) * 64, wcol = (wid & 1) * 32;
  f32x4 acc[4][2] = {};
  const int csrc = ((lane & 3) ^ ((lane >> 3) & 3)) * 8;
  const u16* a_src = ob + (size_t)(row0 + 32 * wid + (lane >> 2)) * Cdim + csrc;
  const u16* b_src = wob + (size_t)(col0 + 16 * wid + (lane >> 2)) * Cdim + csrc;

  auto stage = [&](int buf, int ke) {
    u16* Ad = &As[buf][1024 * wid];
    u16* Bd = &Bs[buf][512 * wid];
    GLD16(a_src + ke, Ad);
    GLD16(a_src + 16 * Cdim + ke, Ad + 512);
    GLD16(b_src + ke, Bd);
  };

  const int rdswz = (kg ^ ((cl >> 1) & 3)) * 8;

  stage(0, 0);
  __syncthreads();
  int cur = 0;
  for (int kk = 0; kk < 32; ++kk) {
    if (kk < 31) stage(cur ^ 1, (kk + 1) * 32);
    const u16* ar = &As[cur][(wrow + cl) * 32 + rdswz];
    const u16* br = &Bs[cur][(wcol + cl) * 32 + rdswz];
    bf16x8 af[4], bfr[2];
#pragma unroll
    for (int mi = 0; mi < 4; ++mi) af[mi] = *(const bf16x8*)(ar + mi * 512);
#pragma unroll
    for (int ni = 0; ni < 2; ++ni) bfr[ni] = *(const bf16x8*)(br + ni * 512);
#pragma unroll
    for (int mi = 0; mi < 4; ++mi)
#pragma unroll
      for (int ni = 0; ni < 2; ++ni)
        acc[mi][ni] = MFMA(af[mi], bfr[ni], acc[mi][ni]);
    __syncthreads();
    cur ^= 1;
  }
#pragma unroll
  for (int mi = 0; mi < 4; ++mi) {
#pragma unroll
    for (int ni = 0; ni < 2; ++ni) {
      int n = col0 + wcol + ni * 16 + cl;
      float bias = bo[n];
#pragma unroll
      for (int j = 0; j < 4; ++j) {
        int r = row0 + wrow + mi * 16 + kg * 4 + j;
        out[(size_t)r * Cdim + n] = acc[mi][ni][j] + bias;
      }
    }
  }
}

extern "C" void kernel_launch(void* const* d_in, const int* in_sizes, int n_in,
                              void* d_out, int out_size, void* d_ws, size_t ws_size,
                              hipStream_t stream) {
  (void)in_sizes; (void)n_in; (void)out_size; (void)ws_size;
  const float* x = (const float*)d_in[0];
  const float* Wq = (const float*)d_in[1];
  const float* Wk = (const float*)d_in[2];
  const float* Wv = (const float*)d_in[3];
  const float* Wo = (const float*)d_in[4];
  const float* bo = (const float*)d_in[5];
  float* out = (float*)d_out;
  char* ws = (char*)d_ws;
  u16* xb = (u16*)(ws);                  // 8 MiB  x bf16 [4096][1024]
  u16* wt = (u16*)(ws + (8u << 20));     // 6 MiB  Wqkv^T bf16 [3072][1024]
  u16* wob = (u16*)(ws + (14u << 20));   // 2 MiB  Wo bf16 [1024][1024]
  u16* qb = (u16*)(ws + (16u << 20));    // 8 MiB  Q (pre-scaled)
  u16* kb = (u16*)(ws + (24u << 20));    // 8 MiB  K
  u16* vtb = (u16*)(ws + (32u << 20));   // 8 MiB  V^T
  u16* ob = (u16*)(ws + (40u << 20));    // 8 MiB  attn out bf16

  k_cast_x<<<4096, 256, 0, stream>>>(x, xb, Bsz * Tsz * Cdim / 4);
  k_cast_x<<<1024, 256, 0, stream>>>(Wo, wob, Cdim * Cdim / 4);
  k_cast_w<<<dim3(16, 48), 256, 0, stream>>>(Wq, Wk, Wv, wt);
  k_gemm_qkv<<<dim3(24, 32), 256, 0, stream>>>(xb, wt, qb, kb, vtb);
  k_attn<<<512, 256, 0, stream>>>(qb, kb, vtb, ob);
  k_gemm_out<<<dim3(16, 32), 256, 0, stream>>>(ob, wob, bo, out);
}

// Round 12
// 116.583 us; speedup vs baseline: 3.9932x; 1.0516x over previous
//
#include <hip/hip_runtime.h>

// MHA forward: B=2 T=2048 C=1024 H=16 D=64, causal, scale 1/sqrt(C)=1/32
// cast -> QKV gemm (3-deep counted-vmcnt pipeline, chunk-swizzled LDS) ->
// folded flash attn (dual rowset/wave, LDS-staged dbuf K/V, swapped QK^T,
// exp2, defer-max, XCD clustering) -> out gemm (same pipeline)

#define Bsz 2
#define Tsz 2048
#define Cdim 1024
#define Hn 16
#define Dh 64

typedef short bf16x8 __attribute__((ext_vector_type(8)));
typedef float f32x4 __attribute__((ext_vector_type(4)));
typedef unsigned short u16;

#define MFMA(a, b, c) __builtin_amdgcn_mfma_f32_16x16x32_bf16(a, b, c, 0, 0, 0)
#define NEGINF (-__builtin_inff())
#define EXP2(x) __builtin_amdgcn_exp2f(x)

#define GLD16(g, l)                                                            \
  __builtin_amdgcn_global_load_lds((const __attribute__((address_space(1))) void*)(g), \
                                   (__attribute__((address_space(3))) void*)(l), 16, 0, 0)

__device__ __forceinline__ u16 f2bf(float f) {
  unsigned u = __builtin_bit_cast(unsigned, f);
  unsigned r = 0x7fffu + ((u >> 16) & 1u);
  return (u16)((u + r) >> 16);
}

__device__ __forceinline__ unsigned cvtpk(float lo, float hi) {
  unsigned r;
  asm("v_cvt_pk_bf16_f32 %0, %1, %2" : "=v"(r) : "v"(lo), "v"(hi));
  return r;
}

// flat f32 -> bf16 cast, 4 elems/thread
__global__ __launch_bounds__(256) void k_cast_x(const float* __restrict__ x,
                                                u16* __restrict__ xb, int n4) {
  int i = blockIdx.x * 256 + threadIdx.x;
  if (i >= n4) return;
  float4 v = reinterpret_cast<const float4*>(x)[i];
  ushort4 o;
  o.x = f2bf(v.x); o.y = f2bf(v.y); o.z = f2bf(v.z); o.w = f2bf(v.w);
  reinterpret_cast<ushort4*>(xb)[i] = o;
}

// Wq/Wk/Wv [H][C][D] f32 -> wt [(m*H+h)*D+d][C] bf16 via LDS tile transpose.
__global__ __launch_bounds__(256) void k_cast_w(const float* __restrict__ Wq,
                                                const float* __restrict__ Wk,
                                                const float* __restrict__ Wv,
                                                u16* __restrict__ wt) {
  __shared__ u16 tile[64][68];
  const int mh = blockIdx.y;
  const int m = mh >> 4, h = mh & 15;
  const float* src = (m == 0 ? Wq : m == 1 ? Wk : Wv) + (size_t)h * Cdim * Dh;
  const int c0 = blockIdx.x * 64;
  const int tid = threadIdx.x;
  const int cc = tid >> 4, d4 = (tid & 15) * 4;
#pragma unroll
  for (int i = 0; i < 4; ++i) {
    int c = i * 16 + cc;
    float4 v = *(const float4*)(src + (size_t)(c0 + c) * Dh + d4);
    tile[d4 + 0][c] = f2bf(v.x);
    tile[d4 + 1][c] = f2bf(v.y);
    tile[d4 + 2][c] = f2bf(v.z);
    tile[d4 + 3][c] = f2bf(v.w);
  }
  __syncthreads();
  const int c4 = (tid & 15) * 4, dd = tid >> 4;
#pragma unroll
  for (int i = 0; i < 4; ++i) {
    int d = i * 16 + dd;
    ushort4 o;
    o.x = tile[d][c4]; o.y = tile[d][c4 + 1];
    o.z = tile[d][c4 + 2]; o.w = tile[d][c4 + 3];
    *(ushort4*)(wt + (size_t)(mh * 64 + d) * Cdim + c0 + c4) = o;
  }
}

// QKV GEMM: 128x128, BK=32, 3-deep counted-vmcnt pipeline (T4): 3 LDS bufs,
// wait vmcnt(8) steady (oldest stage complete, 2 in flight), never 0 in loop.
__global__ __launch_bounds__(256) void k_gemm_qkv(const u16* __restrict__ xb,
                                                  const u16* __restrict__ wt,
                                                  u16* __restrict__ qb,
                                                  u16* __restrict__ kb,
                                                  u16* __restrict__ vtb) {
  __shared__ __align__(16) u16 As[3][4096], Bs[3][4096];
  const int tid = threadIdx.x, lane = tid & 63, wid = tid >> 6;
  const int cl = lane & 15, kg = lane >> 4;
  const int row0 = blockIdx.y * 128, col0 = blockIdx.x * 128;
  const int wrow = (wid >> 1) * 64, wcol = (wid & 1) * 64;
  f32x4 acc[4][4] = {};
  const int csrc = ((lane & 3) ^ ((lane >> 3) & 3)) * 8;
  const u16* a_src = xb + (size_t)(row0 + 32 * wid + (lane >> 2)) * Cdim + csrc;
  const u16* b_src = wt + (size_t)(col0 + 32 * wid + (lane >> 2)) * Cdim + csrc;

  auto stage = [&](int buf, int ke) {
    u16* Ad = &As[buf][1024 * wid];
    u16* Bd = &Bs[buf][1024 * wid];
    GLD16(a_src + ke, Ad);
    GLD16(a_src + 16 * Cdim + ke, Ad + 512);
    GLD16(b_src + ke, Bd);
    GLD16(b_src + 16 * Cdim + ke, Bd + 512);
  };

  const int rdswz = (kg ^ ((cl >> 1) & 3)) * 8;

  stage(0, 0);
  stage(1, 32);
  stage(2, 64);
  for (int kk = 0; kk < 32; ++kk) {
    if (kk < 30)
      asm volatile("s_waitcnt vmcnt(8)" ::: "memory");
    else if (kk == 30)
      asm volatile("s_waitcnt vmcnt(4)" ::: "memory");
    else
      asm volatile("s_waitcnt vmcnt(0)" ::: "memory");
    __builtin_amdgcn_s_barrier();  // all waves: buf[kk%3] ready
    const int cur = kk % 3;
    const u16* ar = &As[cur][(wrow + cl) * 32 + rdswz];
    const u16* br = &Bs[cur][(wcol + cl) * 32 + rdswz];
    bf16x8 af[4], bfr[4];
#pragma unroll
    for (int mi = 0; mi < 4; ++mi) af[mi] = *(const bf16x8*)(ar + mi * 512);
#pragma unroll
    for (int ni = 0; ni < 4; ++ni) bfr[ni] = *(const bf16x8*)(br + ni * 512);
#pragma unroll
    for (int mi = 0; mi < 4; ++mi)
#pragma unroll
      for (int ni = 0; ni < 4; ++ni)
        acc[mi][ni] = MFMA(af[mi], bfr[ni], acc[mi][ni]);
    __builtin_amdgcn_s_barrier();  // all waves done reading buf[kk%3]
    if (kk + 3 < 32) stage(cur, (kk + 3) * 32);
  }
#pragma unroll
  for (int mi = 0; mi < 4; ++mi) {
#pragma unroll
    for (int ni = 0; ni < 4; ++ni) {
      int n = col0 + wcol + ni * 16 + cl;
      int m = n >> 10, h = (n >> 6) & 15, d = n & 63;
#pragma unroll
      for (int j = 0; j < 4; ++j) {
        int r = row0 + wrow + mi * 16 + kg * 4 + j;
        int b = r >> 11, t = r & 2047;
        float av = acc[mi][ni][j];
        if (m == 0) av *= 0.04508422f;  // 1/sqrt(C) * log2(e)
        u16 v = f2bf(av);
        size_t bh = (size_t)(b * Hn + h);
        if (m == 0)
          qb[(bh * Tsz + t) * Dh + d] = v;
        else if (m == 1)
          kb[(bh * Tsz + t) * Dh + d] = v;
        else
          vtb[(bh * Dh + d) * Tsz + t] = v;
      }
    }
  }
}

// ---- folded flash attention with block-shared double-buffered LDS K/V ----
__global__ __launch_bounds__(256, 2) void k_attn(const u16* __restrict__ qb,
                                                 const u16* __restrict__ kb,
                                                 const u16* __restrict__ vtb,
                                                 u16* __restrict__ ob) {
  __shared__ __align__(16) u16 KV[2][8192];
  __shared__ __align__(16) u16 Plds[4][2][1024];
  const int lane = threadIdx.x & 63, wid = threadIdx.x >> 6;
  const int cl = lane & 15, kg = lane >> 4;
  const int bid = blockIdx.x;
  const int kdec = bid >> 3;
  const int p = (bid & 7) + ((kdec >> 4) << 3);
  const int tp = kdec & 15;
  const int h = p & 15, b = p >> 4;
  const int tA = tp, tB = 31 - tp;
  const int qrA = tA * 64 + wid * 16;
  const int qrB = tB * 64 + wid * 16;
  const size_t bh = (size_t)(b * Hn + h);
  const u16* Qp = qb + bh * Tsz * Dh;
  const u16* Kp = kb + bh * Tsz * Dh;
  const u16* Vp = vtb + bh * Dh * Tsz;

  const u16* pk_src[2];
  const u16* pv_src[2];
#pragma unroll
  for (int c = 0; c < 2; ++c) {
    int lo = c * 4096 + wid * 1024 + lane * 16;
    int r = lo >> 7, cb = lo & 127;
    int cbs = cb ^ ((r & 7) << 4);
    pk_src[c] = Kp + r * Dh + (cbs >> 1);
    pv_src[c] = Vp + (size_t)r * Tsz + (cbs >> 1);
  }

  auto stage = [&](int buf, int kt) {
    GLD16(pk_src[0] + kt * 4096, &KV[buf][(wid * 1024) >> 1]);
    GLD16(pk_src[1] + kt * 4096, &KV[buf][(4096 + wid * 1024) >> 1]);
    GLD16(pv_src[0] + kt * 64, &KV[buf][(8192 + wid * 1024) >> 1]);
    GLD16(pv_src[1] + kt * 64, &KV[buf][(12288 + wid * 1024) >> 1]);
  };

  bf16x8 qaA0 = *(const bf16x8*)(Qp + (size_t)(qrA + cl) * Dh + kg * 8);
  bf16x8 qaA1 = *(const bf16x8*)(Qp + (size_t)(qrA + cl) * Dh + 32 + kg * 8);
  bf16x8 qaB0 = *(const bf16x8*)(Qp + (size_t)(qrB + cl) * Dh + kg * 8);
  bf16x8 qaB1 = *(const bf16x8*)(Qp + (size_t)(qrB + cl) * Dh + 32 + kg * 8);

  f32x4 oA[4] = {}, oB[4] = {};
  float mA = NEGINF, lA = 0.f, mB = NEGINF, lB = 0.f;

  char* pbA = (char*)&Plds[wid][0][0];
  char* pbB = (char*)&Plds[wid][1][0];
  const int rdoff0 = ((cl << 7) + (kg << 4)) ^ ((cl & 7) << 4);
  const int rdoff1 = ((cl << 7) + 64 + (kg << 4)) ^ ((cl & 7) << 4);
  const int rowoff = wid * 16;
  const int swz0 = (kg * 16) ^ ((cl & 7) << 4);
  const int swz1 = (kg * 16 + 64) ^ ((cl & 7) << 4);

  auto sm_pv = [&](f32x4 s[4], float& m, float& l, f32x4 o[4],
                   const bf16x8 vf[8], char* pb, bool mask) {
    if (mask) {
#pragma unroll
      for (int nt = 0; nt < 4; ++nt)
#pragma unroll
        for (int j = 0; j < 4; ++j)
          if (nt * 16 + kg * 4 + j > rowoff + cl) s[nt][j] = NEGINF;
    }
    float tm = fmaxf(fmaxf(fmaxf(s[0][0], s[0][1]), fmaxf(s[0][2], s[0][3])),
                     fmaxf(fmaxf(s[1][0], s[1][1]), fmaxf(s[1][2], s[1][3])));
    tm = fmaxf(tm, fmaxf(fmaxf(fmaxf(s[2][0], s[2][1]), fmaxf(s[2][2], s[2][3])),
                         fmaxf(fmaxf(s[3][0], s[3][1]), fmaxf(s[3][2], s[3][3]))));
    if (!__all(tm <= m + 8.0f)) {
      tm = fmaxf(tm, __shfl_xor(tm, 16));
      tm = fmaxf(tm, __shfl_xor(tm, 32));
      float mnew = fmaxf(m, tm);
      float corr = EXP2(m - mnew);
      m = mnew;
      l *= corr;
      float c0 = __shfl(corr, kg * 4 + 0);
      float c1 = __shfl(corr, kg * 4 + 1);
      float c2 = __shfl(corr, kg * 4 + 2);
      float c3 = __shfl(corr, kg * 4 + 3);
#pragma unroll
      for (int dt = 0; dt < 4; ++dt) {
        o[dt][0] *= c0; o[dt][1] *= c1; o[dt][2] *= c2; o[dt][3] *= c3;
      }
    }
    float rs = 0.f;
#pragma unroll
    for (int nt = 0; nt < 4; ++nt)
#pragma unroll
      for (int j = 0; j < 4; ++j) {
        float pv = EXP2(s[nt][j] - m);
        s[nt][j] = pv;
        rs += pv;
      }
    l += rs;
#pragma unroll
    for (int nt = 0; nt < 4; ++nt) {
      uint2 pk;
      pk.x = cvtpk(s[nt][0], s[nt][1]);
      pk.y = cvtpk(s[nt][2], s[nt][3]);
      int waddr = ((cl << 7) + (nt << 5) + (kg << 3)) ^ ((cl & 7) << 4);
      *(uint2*)(pb + waddr) = pk;
    }
    bf16x8 pa0 = *(const bf16x8*)(pb + rdoff0);
    bf16x8 pa1 = *(const bf16x8*)(pb + rdoff1);
    __builtin_amdgcn_s_setprio(1);
#pragma unroll
    for (int dt = 0; dt < 4; ++dt) {
      o[dt] = MFMA(pa0, vf[dt * 2], o[dt]);
      o[dt] = MFMA(pa1, vf[dt * 2 + 1], o[dt]);
    }
    __builtin_amdgcn_s_setprio(0);
  };

  const int ntot = tB + 1;
  stage(0, 0);
  __syncthreads();
  int cur = 0;
  for (int t = 0; t < ntot; ++t) {
    if (t + 1 < ntot) stage(cur ^ 1, t + 1);
    char* kvb = (char*)&KV[cur][0];
    bf16x8 ka[8];
#pragma unroll
    for (int nt = 0; nt < 4; ++nt) {
      int rbase = (nt * 16 + cl) << 7;
      ka[nt * 2] = *(const bf16x8*)(kvb + rbase + swz0);
      ka[nt * 2 + 1] = *(const bf16x8*)(kvb + rbase + swz1);
    }
    f32x4 sB[4];
    __builtin_amdgcn_s_setprio(1);
#pragma unroll
    for (int nt = 0; nt < 4; ++nt) {
      f32x4 z = {};
      z = MFMA(ka[nt * 2], qaB0, z);
      z = MFMA(ka[nt * 2 + 1], qaB1, z);
      sB[nt] = z;
    }
    __builtin_amdgcn_s_setprio(0);
    f32x4 sA[4];
    const bool actA = (t <= tA);
    if (actA) {
      __builtin_amdgcn_s_setprio(1);
#pragma unroll
      for (int nt = 0; nt < 4; ++nt) {
        f32x4 z = {};
        z = MFMA(ka[nt * 2], qaA0, z);
        z = MFMA(ka[nt * 2 + 1], qaA1, z);
        sA[nt] = z;
      }
      __builtin_amdgcn_s_setprio(0);
    }
    bf16x8 vf[8];
#pragma unroll
    for (int dt = 0; dt < 4; ++dt) {
      int rbase = 8192 + ((dt * 16 + cl) << 7);
      vf[dt * 2] = *(const bf16x8*)(kvb + rbase + swz0);
      vf[dt * 2 + 1] = *(const bf16x8*)(kvb + rbase + swz1);
    }
    if (actA) sm_pv(sA, mA, lA, oA, vf, pbA, t == tA);
    sm_pv(sB, mB, lB, oB, vf, pbB, t == tB);
    __syncthreads();
    cur ^= 1;
  }

  lA += __shfl_xor(lA, 16); lA += __shfl_xor(lA, 32);
  lB += __shfl_xor(lB, 16); lB += __shfl_xor(lB, 32);
  float iA0 = 1.f / __shfl(lA, kg * 4 + 0), iA1 = 1.f / __shfl(lA, kg * 4 + 1);
  float iA2 = 1.f / __shfl(lA, kg * 4 + 2), iA3 = 1.f / __shfl(lA, kg * 4 + 3);
  float iB0 = 1.f / __shfl(lB, kg * 4 + 0), iB1 = 1.f / __shfl(lB, kg * 4 + 1);
  float iB2 = 1.f / __shfl(lB, kg * 4 + 2), iB3 = 1.f / __shfl(lB, kg * 4 + 3);
  float invA[4] = {iA0, iA1, iA2, iA3};
  float invB[4] = {iB0, iB1, iB2, iB3};
#pragma unroll
  for (int dt = 0; dt < 4; ++dt)
#pragma unroll
    for (int j = 0; j < 4; ++j) {
      int ta = qrA + kg * 4 + j;
      int tb = qrB + kg * 4 + j;
      ob[(size_t)(b * Tsz + ta) * Cdim + h * Dh + dt * 16 + cl] = f2bf(oA[dt][j] * invA[j]);
      ob[(size_t)(b * Tsz + tb) * Cdim + h * Dh + dt * 16 + cl] = f2bf(oB[dt][j] * invB[j]);
    }
}

// Out GEMM: 128x64 tile, BK=32, 3-deep counted-vmcnt pipeline (3 loads/stage).
__global__ __launch_bounds__(256) void k_gemm_out(const u16* __restrict__ ob,
                                                  const u16* __restrict__ wob,
                                                  const float* __restrict__ bo,
                                                  float* __restrict__ out) {
  __shared__ __align__(16) u16 As[3][4096], Bs[3][2048];
  const int tid = threadIdx.x, lane = tid & 63, wid = tid >> 6;
  const int cl = lane & 15, kg = lane >> 4;
  const int row0 = blockIdx.y * 128, col0 = blockIdx.x * 64;
  const int wrow = (wid >> 1) * 64, wcol = (wid & 1) * 32;
  f32x4 acc[4][2] = {};
  const int csrc = ((lane & 3) ^ ((lane >> 3) & 3)) * 8;
  const u16* a_src = ob + (size_t)(row0 + 32 * wid + (lane >> 2)) * Cdim + csrc;
  const u16* b_src = wob + (size_t)(col0 + 16 * wid + (lane >> 2)) * Cdim + csrc;

  auto stage = [&](int buf, int ke) {
    u16* Ad = &As[buf][1024 * wid];
    u16* Bd = &Bs[buf][512 * wid];
    GLD16(a_src + ke, Ad);
    GLD16(a_src + 16 * Cdim + ke, Ad + 512);
    GLD16(b_src + ke, Bd);
  };

  const int rdswz = (kg ^ ((cl >> 1) & 3)) * 8;

  stage(0, 0);
  stage(1, 32);
  stage(2, 64);
  for (int kk = 0; kk < 32; ++kk) {
    if (kk < 30)
      asm volatile("s_waitcnt vmcnt(6)" ::: "memory");
    else if (kk == 30)
      asm volatile("s_waitcnt vmcnt(3)" ::: "memory");
    else
      asm volatile("s_waitcnt vmcnt(0)" ::: "memory");
    __builtin_amdgcn_s_barrier();
    const int cur = kk % 3;
    const u16* ar = &As[cur][(wrow + cl) * 32 + rdswz];
    const u16* br = &Bs[cur][(wcol + cl) * 32 + rdswz];
    bf16x8 af[4], bfr[2];
#pragma unroll
    for (int mi = 0; mi < 4; ++mi) af[mi] = *(const bf16x8*)(ar + mi * 512);
#pragma unroll
    for (int ni = 0; ni < 2; ++ni) bfr[ni] = *(const bf16x8*)(br + ni * 512);
#pragma unroll
    for (int mi = 0; mi < 4; ++mi)
#pragma unroll
      for (int ni = 0; ni < 2; ++ni)
        acc[mi][ni] = MFMA(af[mi], bfr[ni], acc[mi][ni]);
    __builtin_amdgcn_s_barrier();
    if (kk + 3 < 32) stage(cur, (kk + 3) * 32);
  }
#pragma unroll
  for (int mi = 0; mi < 4; ++mi) {
#pragma unroll
    for (int ni = 0; ni < 2; ++ni) {
      int n = col0 + wcol + ni * 16 + cl;
      float bias = bo[n];
#pragma unroll
      for (int j = 0; j < 4; ++j) {
        int r = row0 + wrow + mi * 16 + kg * 4 + j;
        out[(size_t)r * Cdim + n] = acc[mi][ni][j] + bias;
      }
    }
  }
}

extern "C" void kernel_launch(void* const* d_in, const int* in_sizes, int n_in,
                              void* d_out, int out_size, void* d_ws, size_t ws_size,
                              hipStream_t stream) {
  (void)in_sizes; (void)n_in; (void)out_size; (void)ws_size;
  const float* x = (const float*)d_in[0];
  const float* Wq = (const float*)d_in[1];
  const float* Wk = (const float*)d_in[2];
  const float* Wv = (const float*)d_in[3];
  const float* Wo = (const float*)d_in[4];
  const float* bo = (const float*)d_in[5];
  float* out = (float*)d_out;
  char* ws = (char*)d_ws;
  u16* xb = (u16*)(ws);                  // 8 MiB  x bf16 [4096][1024]
  u16* wt = (u16*)(ws + (8u << 20));     // 6 MiB  Wqkv^T bf16 [3072][1024]
  u16* wob = (u16*)(ws + (14u << 20));   // 2 MiB  Wo bf16 [1024][1024]
  u16* qb = (u16*)(ws + (16u << 20));    // 8 MiB  Q (pre-scaled)
  u16* kb = (u16*)(ws + (24u << 20));    // 8 MiB  K
  u16* vtb = (u16*)(ws + (32u << 20));   // 8 MiB  V^T
  u16* ob = (u16*)(ws + (40u << 20));    // 8 MiB  attn out bf16

  k_cast_x<<<4096, 256, 0, stream>>>(x, xb, Bsz * Tsz * Cdim / 4);
  k_cast_x<<<1024, 256, 0, stream>>>(Wo, wob, Cdim * Cdim / 4);
  k_cast_w<<<dim3(16, 48), 256, 0, stream>>>(Wq, Wk, Wv, wt);
  k_gemm_qkv<<<dim3(24, 32), 256, 0, stream>>>(xb, wt, qb, kb, vtb);
  k_attn<<<512, 256, 0, stream>>>(qb, kb, vtb, ob);
  k_gemm_out<<<dim3(16, 32), 256, 0, stream>>>(ob, wob, bo, out);
}

// Round 13
// 112.480 us; speedup vs baseline: 4.1388x; 1.0365x over previous
//
#include <hip/hip_runtime.h>

// MHA forward: B=2 T=2048 C=1024 H=16 D=64, causal, scale 1/sqrt(C)=1/32
// cast -> QKV gemm (3-deep counted-vmcnt pipeline, chunk-swizzled LDS) ->
// flash attn (1024 blocks, 1 q-tile/block, LDS-staged dbuf K/V, swapped QK^T,
// exp2, defer-max, XCD clustering, longest-first) -> out gemm (same pipeline)

#define Bsz 2
#define Tsz 2048
#define Cdim 1024
#define Hn 16
#define Dh 64

typedef short bf16x8 __attribute__((ext_vector_type(8)));
typedef float f32x4 __attribute__((ext_vector_type(4)));
typedef unsigned short u16;

#define MFMA(a, b, c) __builtin_amdgcn_mfma_f32_16x16x32_bf16(a, b, c, 0, 0, 0)
#define NEGINF (-__builtin_inff())
#define EXP2(x) __builtin_amdgcn_exp2f(x)

#define GLD16(g, l)                                                            \
  __builtin_amdgcn_global_load_lds((const __attribute__((address_space(1))) void*)(g), \
                                   (__attribute__((address_space(3))) void*)(l), 16, 0, 0)

__device__ __forceinline__ u16 f2bf(float f) {
  unsigned u = __builtin_bit_cast(unsigned, f);
  unsigned r = 0x7fffu + ((u >> 16) & 1u);
  return (u16)((u + r) >> 16);
}

__device__ __forceinline__ unsigned cvtpk(float lo, float hi) {
  unsigned r;
  asm("v_cvt_pk_bf16_f32 %0, %1, %2" : "=v"(r) : "v"(lo), "v"(hi));
  return r;
}

// flat f32 -> bf16 cast, 4 elems/thread
__global__ __launch_bounds__(256) void k_cast_x(const float* __restrict__ x,
                                                u16* __restrict__ xb, int n4) {
  int i = blockIdx.x * 256 + threadIdx.x;
  if (i >= n4) return;
  float4 v = reinterpret_cast<const float4*>(x)[i];
  ushort4 o;
  o.x = f2bf(v.x); o.y = f2bf(v.y); o.z = f2bf(v.z); o.w = f2bf(v.w);
  reinterpret_cast<ushort4*>(xb)[i] = o;
}

// Wq/Wk/Wv [H][C][D] f32 -> wt [(m*H+h)*D+d][C] bf16 via LDS tile transpose.
__global__ __launch_bounds__(256) void k_cast_w(const float* __restrict__ Wq,
                                                const float* __restrict__ Wk,
                                                const float* __restrict__ Wv,
                                                u16* __restrict__ wt) {
  __shared__ u16 tile[64][68];
  const int mh = blockIdx.y;
  const int m = mh >> 4, h = mh & 15;
  const float* src = (m == 0 ? Wq : m == 1 ? Wk : Wv) + (size_t)h * Cdim * Dh;
  const int c0 = blockIdx.x * 64;
  const int tid = threadIdx.x;
  const int cc = tid >> 4, d4 = (tid & 15) * 4;
#pragma unroll
  for (int i = 0; i < 4; ++i) {
    int c = i * 16 + cc;
    float4 v = *(const float4*)(src + (size_t)(c0 + c) * Dh + d4);
    tile[d4 + 0][c] = f2bf(v.x);
    tile[d4 + 1][c] = f2bf(v.y);
    tile[d4 + 2][c] = f2bf(v.z);
    tile[d4 + 3][c] = f2bf(v.w);
  }
  __syncthreads();
  const int c4 = (tid & 15) * 4, dd = tid >> 4;
#pragma unroll
  for (int i = 0; i < 4; ++i) {
    int d = i * 16 + dd;
    ushort4 o;
    o.x = tile[d][c4]; o.y = tile[d][c4 + 1];
    o.z = tile[d][c4 + 2]; o.w = tile[d][c4 + 3];
    *(ushort4*)(wt + (size_t)(mh * 64 + d) * Cdim + c0 + c4) = o;
  }
}

// QKV GEMM: 128x128, BK=32, 3-deep counted-vmcnt pipeline, chunk-swizzled LDS.
__global__ __launch_bounds__(256) void k_gemm_qkv(const u16* __restrict__ xb,
                                                  const u16* __restrict__ wt,
                                                  u16* __restrict__ qb,
                                                  u16* __restrict__ kb,
                                                  u16* __restrict__ vtb) {
  __shared__ __align__(16) u16 As[3][4096], Bs[3][4096];
  const int tid = threadIdx.x, lane = tid & 63, wid = tid >> 6;
  const int cl = lane & 15, kg = lane >> 4;
  const int row0 = blockIdx.y * 128, col0 = blockIdx.x * 128;
  const int wrow = (wid >> 1) * 64, wcol = (wid & 1) * 64;
  f32x4 acc[4][4] = {};
  const int csrc = ((lane & 3) ^ ((lane >> 3) & 3)) * 8;
  const u16* a_src = xb + (size_t)(row0 + 32 * wid + (lane >> 2)) * Cdim + csrc;
  const u16* b_src = wt + (size_t)(col0 + 32 * wid + (lane >> 2)) * Cdim + csrc;

  auto stage = [&](int buf, int ke) {
    u16* Ad = &As[buf][1024 * wid];
    u16* Bd = &Bs[buf][1024 * wid];
    GLD16(a_src + ke, Ad);
    GLD16(a_src + 16 * Cdim + ke, Ad + 512);
    GLD16(b_src + ke, Bd);
    GLD16(b_src + 16 * Cdim + ke, Bd + 512);
  };

  const int rdswz = (kg ^ ((cl >> 1) & 3)) * 8;

  stage(0, 0);
  stage(1, 32);
  stage(2, 64);
  for (int kk = 0; kk < 32; ++kk) {
    if (kk < 30)
      asm volatile("s_waitcnt vmcnt(8)" ::: "memory");
    else if (kk == 30)
      asm volatile("s_waitcnt vmcnt(4)" ::: "memory");
    else
      asm volatile("s_waitcnt vmcnt(0)" ::: "memory");
    __builtin_amdgcn_s_barrier();  // all waves: buf[kk%3] ready
    const int cur = kk % 3;
    const u16* ar = &As[cur][(wrow + cl) * 32 + rdswz];
    const u16* br = &Bs[cur][(wcol + cl) * 32 + rdswz];
    bf16x8 af[4], bfr[4];
#pragma unroll
    for (int mi = 0; mi < 4; ++mi) af[mi] = *(const bf16x8*)(ar + mi * 512);
#pragma unroll
    for (int ni = 0; ni < 4; ++ni) bfr[ni] = *(const bf16x8*)(br + ni * 512);
#pragma unroll
    for (int mi = 0; mi < 4; ++mi)
#pragma unroll
      for (int ni = 0; ni < 4; ++ni)
        acc[mi][ni] = MFMA(af[mi], bfr[ni], acc[mi][ni]);
    __builtin_amdgcn_s_barrier();  // all waves done reading buf[kk%3]
    if (kk + 3 < 32) stage(cur, (kk + 3) * 32);
  }
#pragma unroll
  for (int mi = 0; mi < 4; ++mi) {
#pragma unroll
    for (int ni = 0; ni < 4; ++ni) {
      int n = col0 + wcol + ni * 16 + cl;
      int m = n >> 10, h = (n >> 6) & 15, d = n & 63;
#pragma unroll
      for (int j = 0; j < 4; ++j) {
        int r = row0 + wrow + mi * 16 + kg * 4 + j;
        int b = r >> 11, t = r & 2047;
        float av = acc[mi][ni][j];
        if (m == 0) av *= 0.04508422f;  // 1/sqrt(C) * log2(e)
        u16 v = f2bf(av);
        size_t bh = (size_t)(b * Hn + h);
        if (m == 0)
          qb[(bh * Tsz + t) * Dh + d] = v;
        else if (m == 1)
          kb[(bh * Tsz + t) * Dh + d] = v;
        else
          vtb[(bh * Dh + d) * Tsz + t] = v;
      }
    }
  }
}

// ---- flash attention: 1024 blocks, 1 q-tile/block, LDS-staged dbuf K/V ----
// Grid 1024: xcd = bid&7; s = bid>>3; t = 31-(s>>2) (longest first);
// bh p = xcd + 8*(s&3). All blocks of one (b,h) share an XCD. 4 waves/block,
// wave wid owns q-rows [t*64+wid*16,+16). LDS 40KB -> 4 blocks/CU.
__global__ __launch_bounds__(256, 4) void k_attn(const u16* __restrict__ qb,
                                                 const u16* __restrict__ kb,
                                                 const u16* __restrict__ vtb,
                                                 u16* __restrict__ ob) {
  __shared__ __align__(16) u16 KV[2][8192];   // [buf][ K: 0..4095 | V: 4096..8191 ]
  __shared__ __align__(16) u16 Plds[4][1024]; // per-wave P roundtrip
  const int lane = threadIdx.x & 63, wid = threadIdx.x >> 6;
  const int cl = lane & 15, kg = lane >> 4;
  const int s = blockIdx.x >> 3;
  const int t = 31 - (s >> 2);
  const int p = (blockIdx.x & 7) + 8 * (s & 3);
  const int h = p & 15, b = p >> 4;
  const int qr = t * 64 + wid * 16;
  const size_t bh = (size_t)(b * Hn + h);
  const u16* Qp = qb + bh * Tsz * Dh;
  const u16* Kp = kb + bh * Tsz * Dh;
  const u16* Vp = vtb + bh * Dh * Tsz;

  const u16* pk_src[2];
  const u16* pv_src[2];
#pragma unroll
  for (int c = 0; c < 2; ++c) {
    int lo = c * 4096 + wid * 1024 + lane * 16;
    int r = lo >> 7, cb = lo & 127;
    int cbs = cb ^ ((r & 7) << 4);
    pk_src[c] = Kp + r * Dh + (cbs >> 1);
    pv_src[c] = Vp + (size_t)r * Tsz + (cbs >> 1);
  }

  auto stage = [&](int buf, int kt) {
    GLD16(pk_src[0] + kt * 4096, &KV[buf][(wid * 1024) >> 1]);
    GLD16(pk_src[1] + kt * 4096, &KV[buf][(4096 + wid * 1024) >> 1]);
    GLD16(pv_src[0] + kt * 64, &KV[buf][(8192 + wid * 1024) >> 1]);
    GLD16(pv_src[1] + kt * 64, &KV[buf][(12288 + wid * 1024) >> 1]);
  };

  bf16x8 qa0 = *(const bf16x8*)(Qp + (size_t)(qr + cl) * Dh + kg * 8);
  bf16x8 qa1 = *(const bf16x8*)(Qp + (size_t)(qr + cl) * Dh + 32 + kg * 8);

  f32x4 o[4] = {};
  float m = NEGINF, l = 0.f;

  char* pb = (char*)&Plds[wid][0];
  const int rdoff0 = ((cl << 7) + (kg << 4)) ^ ((cl & 7) << 4);
  const int rdoff1 = ((cl << 7) + 64 + (kg << 4)) ^ ((cl & 7) << 4);
  const int rowoff = wid * 16;
  const int swz0 = (kg * 16) ^ ((cl & 7) << 4);
  const int swz1 = (kg * 16 + 64) ^ ((cl & 7) << 4);

  stage(0, 0);
  __syncthreads();
  int cur = 0;
  for (int kt = 0; kt <= t; ++kt) {
    if (kt < t) stage(cur ^ 1, kt + 1);
    char* kvb = (char*)&KV[cur][0];
    // K frags from LDS
    bf16x8 ka[8];
#pragma unroll
    for (int nt = 0; nt < 4; ++nt) {
      int rbase = (nt * 16 + cl) << 7;
      ka[nt * 2] = *(const bf16x8*)(kvb + rbase + swz0);
      ka[nt * 2 + 1] = *(const bf16x8*)(kvb + rbase + swz1);
    }
    f32x4 sv[4];
    __builtin_amdgcn_s_setprio(1);
#pragma unroll
    for (int nt = 0; nt < 4; ++nt) {
      f32x4 z = {};
      z = MFMA(ka[nt * 2], qa0, z);
      z = MFMA(ka[nt * 2 + 1], qa1, z);
      sv[nt] = z;
    }
    __builtin_amdgcn_s_setprio(0);
    // V frags from LDS
    bf16x8 vf[8];
#pragma unroll
    for (int dt = 0; dt < 4; ++dt) {
      int rbase = 8192 + ((dt * 16 + cl) << 7);
      vf[dt * 2] = *(const bf16x8*)(kvb + rbase + swz0);
      vf[dt * 2 + 1] = *(const bf16x8*)(kvb + rbase + swz1);
    }
    if (kt == t) {  // diag tile mask
#pragma unroll
      for (int nt = 0; nt < 4; ++nt)
#pragma unroll
        for (int j = 0; j < 4; ++j)
          if (nt * 16 + kg * 4 + j > rowoff + cl) sv[nt][j] = NEGINF;
    }
    float tm = fmaxf(fmaxf(fmaxf(sv[0][0], sv[0][1]), fmaxf(sv[0][2], sv[0][3])),
                     fmaxf(fmaxf(sv[1][0], sv[1][1]), fmaxf(sv[1][2], sv[1][3])));
    tm = fmaxf(tm, fmaxf(fmaxf(fmaxf(sv[2][0], sv[2][1]), fmaxf(sv[2][2], sv[2][3])),
                         fmaxf(fmaxf(sv[3][0], sv[3][1]), fmaxf(sv[3][2], sv[3][3]))));
    if (!__all(tm <= m + 8.0f)) {
      tm = fmaxf(tm, __shfl_xor(tm, 16));
      tm = fmaxf(tm, __shfl_xor(tm, 32));
      float mnew = fmaxf(m, tm);
      float corr = EXP2(m - mnew);
      m = mnew;
      l *= corr;
      float c0 = __shfl(corr, kg * 4 + 0);
      float c1 = __shfl(corr, kg * 4 + 1);
      float c2 = __shfl(corr, kg * 4 + 2);
      float c3 = __shfl(corr, kg * 4 + 3);
#pragma unroll
      for (int dt = 0; dt < 4; ++dt) {
        o[dt][0] *= c0; o[dt][1] *= c1; o[dt][2] *= c2; o[dt][3] *= c3;
      }
    }
    float rs = 0.f;
#pragma unroll
    for (int nt = 0; nt < 4; ++nt)
#pragma unroll
      for (int j = 0; j < 4; ++j) {
        float pv = EXP2(sv[nt][j] - m);
        sv[nt][j] = pv;
        rs += pv;
      }
    l += rs;
#pragma unroll
    for (int nt = 0; nt < 4; ++nt) {
      uint2 pk;
      pk.x = cvtpk(sv[nt][0], sv[nt][1]);
      pk.y = cvtpk(sv[nt][2], sv[nt][3]);
      int waddr = ((cl << 7) + (nt << 5) + (kg << 3)) ^ ((cl & 7) << 4);
      *(uint2*)(pb + waddr) = pk;
    }
    bf16x8 pa0 = *(const bf16x8*)(pb + rdoff0);
    bf16x8 pa1 = *(const bf16x8*)(pb + rdoff1);
    __builtin_amdgcn_s_setprio(1);
#pragma unroll
    for (int dt = 0; dt < 4; ++dt) {
      o[dt] = MFMA(pa0, vf[dt * 2], o[dt]);
      o[dt] = MFMA(pa1, vf[dt * 2 + 1], o[dt]);
    }
    __builtin_amdgcn_s_setprio(0);
    __syncthreads();  // drains next-tile gld_lds + protects buffer reuse
    cur ^= 1;
  }

  // epilogue: finish lazy l reduction, broadcast 1/l per O row
  l += __shfl_xor(l, 16);
  l += __shfl_xor(l, 32);
  float i0 = 1.f / __shfl(l, kg * 4 + 0), i1 = 1.f / __shfl(l, kg * 4 + 1);
  float i2 = 1.f / __shfl(l, kg * 4 + 2), i3 = 1.f / __shfl(l, kg * 4 + 3);
  float inv[4] = {i0, i1, i2, i3};
#pragma unroll
  for (int dt = 0; dt < 4; ++dt)
#pragma unroll
    for (int j = 0; j < 4; ++j) {
      int tr = qr + kg * 4 + j;
      ob[(size_t)(b * Tsz + tr) * Cdim + h * Dh + dt * 16 + cl] = f2bf(o[dt][j] * inv[j]);
    }
}

// Out GEMM: 128x64 tile, BK=32, 3-deep counted-vmcnt pipeline.
__global__ __launch_bounds__(256) void k_gemm_out(const u16* __restrict__ ob,
                                                  const u16* __restrict__ wob,
                                                  const float* __restrict__ bo,
                                                  float* __restrict__ out) {
  __shared__ __align__(16) u16 As[3][4096], Bs[3][2048];
  const int tid = threadIdx.x, lane = tid & 63, wid = tid >> 6;
  const int cl = lane & 15, kg = lane >> 4;
  const int row0 = blockIdx.y * 128, col0 = blockIdx.x * 64;
  const int wrow = (wid >> 1) * 64, wcol = (wid & 1) * 32;
  f32x4 acc[4][2] = {};
  const int csrc = ((lane & 3) ^ ((lane >> 3) & 3)) * 8;
  const u16* a_src = ob + (size_t)(row0 + 32 * wid + (lane >> 2)) * Cdim + csrc;
  const u16* b_src = wob + (size_t)(col0 + 16 * wid + (lane >> 2)) * Cdim + csrc;

  auto stage = [&](int buf, int ke) {
    u16* Ad = &As[buf][1024 * wid];
    u16* Bd = &Bs[buf][512 * wid];
    GLD16(a_src + ke, Ad);
    GLD16(a_src + 16 * Cdim + ke, Ad + 512);
    GLD16(b_src + ke, Bd);
  };

  const int rdswz = (kg ^ ((cl >> 1) & 3)) * 8;

  stage(0, 0);
  stage(1, 32);
  stage(2, 64);
  for (int kk = 0; kk < 32; ++kk) {
    if (kk < 30)
      asm volatile("s_waitcnt vmcnt(6)" ::: "memory");
    else if (kk == 30)
      asm volatile("s_waitcnt vmcnt(3)" ::: "memory");
    else
      asm volatile("s_waitcnt vmcnt(0)" ::: "memory");
    __builtin_amdgcn_s_barrier();
    const int cur = kk % 3;
    const u16* ar = &As[cur][(wrow + cl) * 32 + rdswz];
    const u16* br = &Bs[cur][(wcol + cl) * 32 + rdswz];
    bf16x8 af[4], bfr[2];
#pragma unroll
    for (int mi = 0; mi < 4; ++mi) af[mi] = *(const bf16x8*)(ar + mi * 512);
#pragma unroll
    for (int ni = 0; ni < 2; ++ni) bfr[ni] = *(const bf16x8*)(br + ni * 512);
#pragma unroll
    for (int mi = 0; mi < 4; ++mi)
#pragma unroll
      for (int ni = 0; ni < 2; ++ni)
        acc[mi][ni] = MFMA(af[mi], bfr[ni], acc[mi][ni]);
    __builtin_amdgcn_s_barrier();
    if (kk + 3 < 32) stage(cur, (kk + 3) * 32);
  }
#pragma unroll
  for (int mi = 0; mi < 4; ++mi) {
#pragma unroll
    for (int ni = 0; ni < 2; ++ni) {
      int n = col0 + wcol + ni * 16 + cl;
      float bias = bo[n];
#pragma unroll
      for (int j = 0; j < 4; ++j) {
        int r = row0 + wrow + mi * 16 + kg * 4 + j;
        out[(size_t)r * Cdim + n] = acc[mi][ni][j] + bias;
      }
    }
  }
}

extern "C" void kernel_launch(void* const* d_in, const int* in_sizes, int n_in,
                              void* d_out, int out_size, void* d_ws, size_t ws_size,
                              hipStream_t stream) {
  (void)in_sizes; (void)n_in; (void)out_size; (void)ws_size;
  const float* x = (const float*)d_in[0];
  const float* Wq = (const float*)d_in[1];
  const float* Wk = (const float*)d_in[2];
  const float* Wv = (const float*)d_in[3];
  const float* Wo = (const float*)d_in[4];
  const float* bo = (const float*)d_in[5];
  float* out = (float*)d_out;
  char* ws = (char*)d_ws;
  u16* xb = (u16*)(ws);                  // 8 MiB  x bf16 [4096][1024]
  u16* wt = (u16*)(ws + (8u << 20));     // 6 MiB  Wqkv^T bf16 [3072][1024]
  u16* wob = (u16*)(ws + (14u << 20));   // 2 MiB  Wo bf16 [1024][1024]
  u16* qb = (u16*)(ws + (16u << 20));    // 8 MiB  Q (pre-scaled)
  u16* kb = (u16*)(ws + (24u << 20));    // 8 MiB  K
  u16* vtb = (u16*)(ws + (32u << 20));   // 8 MiB  V^T
  u16* ob = (u16*)(ws + (40u << 20));    // 8 MiB  attn out bf16

  k_cast_x<<<4096, 256, 0, stream>>>(x, xb, Bsz * Tsz * Cdim / 4);
  k_cast_x<<<1024, 256, 0, stream>>>(Wo, wob, Cdim * Cdim / 4);
  k_cast_w<<<dim3(16, 48), 256, 0, stream>>>(Wq, Wk, Wv, wt);
  k_gemm_qkv<<<dim3(24, 32), 256, 0, stream>>>(xb, wt, qb, kb, vtb);
  k_attn<<<1024, 256, 0, stream>>>(qb, kb, vtb, ob);
  k_gemm_out<<<dim3(16, 32), 256, 0, stream>>>(ob, wob, bo, out);
}